// Round 8
// baseline (211.424 us; speedup 1.0000x reference)
//
#include <hip/hip_runtime.h>

// Problem constants (B=2,S=1024 -> T=2048; H=1024, I=512, SI=2048, E=8, TOPK=2)
#define T_TOK 2048
#define H_DIM 1024
#define I_DIM 512
#define SI_DIM 2048
#define E_NUM 8
#define NSLOT 4096  // total expert slots: exactly 2 per token

typedef __attribute__((ext_vector_type(8))) short short8;   // 8 x bf16 (4 VGPRs)
typedef __attribute__((ext_vector_type(4))) float floatx4;  // MFMA C/D

// fp32 -> bf16 round-to-nearest-even
__device__ inline unsigned short f2bf(float f) {
  unsigned u = __builtin_bit_cast(unsigned, f);
  u = (u + 0x7FFFu + ((u >> 16) & 1u)) >> 16;
  return (unsigned short)u;
}
__device__ inline float bf2f(unsigned short u) {
  return __builtin_bit_cast(float, (unsigned)u << 16);
}

// async global->LDS, 16B per lane; LDS dest = wave-uniform base + lane*16
__device__ inline void gl_lds16(const void* g, void* l) {
  __builtin_amdgcn_global_load_lds(
      (const __attribute__((address_space(1))) unsigned int*)g,
      (__attribute__((address_space(3))) unsigned int*)l, 16, 0, 0);
}

// ---------------------------------------------------------------------------
// Fused cast + router. Blocks [0,512): router (latency-bound, dispatched
// first so it overlaps the BW-bound cast flood). Blocks [512,20992): cast.
// ---------------------------------------------------------------------------
__global__ __launch_bounds__(256) void cast_router(
    const float* __restrict__ x, const float* __restrict__ rw,
    const float* __restrict__ segw,
    const float* __restrict__ s1, const float* __restrict__ s2,
    const float* __restrict__ s3, const float* __restrict__ s4,
    const float* __restrict__ s5,
    unsigned short* __restrict__ d0, unsigned short* __restrict__ d1,
    unsigned short* __restrict__ d2, unsigned short* __restrict__ d3,
    unsigned short* __restrict__ d4, unsigned short* __restrict__ d5,
    int* __restrict__ top2, float2* __restrict__ w01, float* __restrict__ sg) {
  const int bid = blockIdx.x;
  if (bid < 512) {
    // ---- router: one wave per token, fp32 logits (matches ref numerics) ----
    int t = bid * 4 + (threadIdx.x >> 6);
    int lane = threadIdx.x & 63;
    const float* xt = x + (long)t * H_DIM;
    float xv[16];
#pragma unroll
    for (int j = 0; j < 16; ++j) xv[j] = xt[j * 64 + lane];
    float dots[9];
#pragma unroll
    for (int e = 0; e < 8; ++e) {
      const float* w = rw + e * H_DIM;
      float s = 0.f;
#pragma unroll
      for (int j = 0; j < 16; ++j) s += xv[j] * w[j * 64 + lane];
      dots[e] = s;
    }
    {
      float s = 0.f;
#pragma unroll
      for (int j = 0; j < 16; ++j) s += xv[j] * segw[j * 64 + lane];
      dots[8] = s;
    }
#pragma unroll
    for (int off = 32; off > 0; off >>= 1) {
#pragma unroll
      for (int e = 0; e < 9; ++e) dots[e] += __shfl_xor(dots[e], off, 64);
    }
    if (lane == 0) {
      int e0 = 0;
      for (int e = 1; e < 8; ++e)
        if (dots[e] > dots[e0]) e0 = e;
      int e1 = (e0 == 0) ? 1 : 0;
      for (int e = 0; e < 8; ++e)
        if (e != e0 && dots[e] > dots[e1]) e1 = e;
      float p1 = expf(dots[e1] - dots[e0]);
      top2[t] = e0 | (e1 << 8);
      w01[t] = make_float2(1.f / (1.f + p1), p1 / (1.f + p1));
      sg[t] = 1.f / (1.f + expf(-dots[8]));
    }
  } else {
    // ---- cast: 6 fp32 segments -> bf16, 4 elems/thread ----
    long g = (long)(bid - 512) * 256 + threadIdx.x;
    const float* s;
    unsigned short* d;
    long off;
    if (g < 524288L)       { s = x;  d = d0; off = g; }            // x
    else if (g < 2621440L) { s = s1; d = d1; off = g - 524288L; }  // gate_up
    else if (g < 3670016L) { s = s2; d = d2; off = g - 2621440L; } // down
    else if (g < 4194304L) { s = s3; d = d3; off = g - 3670016L; } // shared_gate
    else if (g < 4718592L) { s = s4; d = d4; off = g - 4194304L; } // shared_up
    else                   { s = s5; d = d5; off = g - 4718592L; } // shared_down
    float4 v = ((const float4*)s)[off];
    ushort4 o;
    o.x = f2bf(v.x); o.y = f2bf(v.y); o.z = f2bf(v.z); o.w = f2bf(v.w);
    ((ushort4*)d)[off] = o;
  }
}

// ---------------------------------------------------------------------------
// Router phase 2: one block per expert; block-wide scan -> compact slot list
// (global base = #assignments to experts < e) + tok_slot back-pointers.
// ---------------------------------------------------------------------------
__global__ __launch_bounds__(256) void build_lists(
    const int* __restrict__ top2, int* __restrict__ cnt, int* __restrict__ ebase,
    int* __restrict__ slot_token, int* __restrict__ tok_slot) {
  const int e = blockIdx.x;
  const int tid = threadIdx.x;
  const int lane = tid & 63, wid = tid >> 6;
  __shared__ int wsum[4], wbelow[4];
  const int base_t = tid * 8;  // 2048 / 256
  int mk[8], kk[8];
  int c = 0, below = 0;
#pragma unroll
  for (int j = 0; j < 8; ++j) {
    int p = top2[base_t + j];
    int e0 = p & 0xFF, e1 = (p >> 8) & 0xFF;
    below += (e0 < e) + (e1 < e);
    int m = 0, k = 0;
    if (e0 == e) { m = 1; k = 0; }
    else if (e1 == e) { m = 1; k = 1; }
    mk[j] = m; kk[j] = k;
    c += m;
  }
  int inc = c;
#pragma unroll
  for (int off = 1; off < 64; off <<= 1) {
    int n = __shfl_up(inc, off, 64);
    if (lane >= off) inc += n;
  }
  int bsum = below;
#pragma unroll
  for (int off = 32; off > 0; off >>= 1) bsum += __shfl_xor(bsum, off, 64);
  if (lane == 63) wsum[wid] = inc;
  if (lane == 0) wbelow[wid] = bsum;
  __syncthreads();
  int woff = 0;
#pragma unroll
  for (int i = 0; i < 4; ++i)
    if (i < wid) woff += wsum[i];
  int baseE = wbelow[0] + wbelow[1] + wbelow[2] + wbelow[3];
  int pos = baseE + woff + inc - c;
#pragma unroll
  for (int j = 0; j < 8; ++j) {
    if (mk[j]) {
      slot_token[pos] = base_t + j;
      tok_slot[2 * (base_t + j) + kk[j]] = pos;
      pos++;
    }
  }
  if (tid == 255) cnt[e] = woff + inc;
  if (tid == 0) ebase[e] = baseE;
}

// ---------------------------------------------------------------------------
// Fused SwiGLU GEMM body: act = silu(A@Bg^T)*(A@Bu^T), bf16, fp32 acc.
// BM=256, BK=32, 512 threads = 8 waves (4m x 2n); wave tile 64 x (BN/2) for
// both G and U. Per wave-iter (BN=128): 12 ds_read_b128 -> 32 MFMA.
// Double-buffered LDS (1 barrier/iter) + XOR bank swizzle (0 conflicts).
// Geometry: ~1 active block per CU, single residency generation.
// ---------------------------------------------------------------------------
template <bool GATHER, int BN>
__device__ __forceinline__ void swiglu_body(
    char* smem, int bx, int by, int e,
    const unsigned short* __restrict__ A, const unsigned short* __restrict__ Bg,
    const unsigned short* __restrict__ Bu, unsigned short* __restrict__ Out,
    const int* __restrict__ slot_token, const int* __restrict__ cnt,
    const int* __restrict__ ebase, int N, int K, long estrideB) {
  constexpr int BM = 256, BK = 32;
  constexpr int NT = BN / 32;          // n-tiles of 16 per wave
  constexpr int ATILE = BM * BK;       // ushorts
  constexpr int BTILE = BN * BK;
  const int tid = threadIdx.x;
  const int lane = tid & 63;
  const int wid = tid >> 6;  // 0..7
  const int wm = wid & 3;    // 4 m-positions (64 rows each)
  const int wn = wid >> 2;   // 2 n-positions (BN/2 cols each)
  const int m0 = by * BM;
  const int n0 = bx * BN;
  int Meff = 0, baseE = 0;
  if (GATHER) {
    Meff = cnt[e];
    if (m0 >= Meff) return;
    baseE = ebase[e];
  }
  const unsigned short* BgE = Bg + (long)e * estrideB;
  const unsigned short* BuE = Bu + (long)e * estrideB;

  unsigned short* As = (unsigned short*)smem;  // [2][256*32]
  unsigned short* Bgs = As + 2 * ATILE;        // [2][BN*32]
  unsigned short* Bus = Bgs + 2 * BTILE;       // [2][BN*32]

  const int lrow = lane >> 2;  // 16 rows / 1KB chunk
  const int lcol = (((lane & 3) ^ ((lrow >> 1) & 3)) << 4);  // swizzled 16B col

  // A staging: 256 rows = 8 waves x 2 chunks of 16 rows
  const char* aP[2];
#pragma unroll
  for (int i = 0; i < 2; ++i) {
    int m = m0 + wid * 32 + i * 16 + lrow;
    long row;
    if (GATHER) {
      int mm = (m < Meff - 1) ? m : (Meff - 1);  // clamp tail to valid slot
      row = slot_token[baseE + mm];
    } else {
      row = m;
    }
    aP[i] = (const char*)A + row * (long)(K * 2) + lcol;
  }
  // B staging: BN=128 -> each wave stages 1 G-chunk + 1 U-chunk;
  //            BN=64  -> waves 0-3 stage G, waves 4-7 stage U (1 chunk each).
  const char* bgP = nullptr;
  const char* buP = nullptr;
  const char* bsP = nullptr;
  unsigned short* bDst = nullptr;
  if constexpr (BN == 128) {
    int n = n0 + wid * 16 + lrow;
    bgP = (const char*)BgE + (long)n * (K * 2) + lcol;
    buP = (const char*)BuE + (long)n * (K * 2) + lcol;
  } else {
    int cw = wid & 3;  // chunk within the 64-row operand
    int n = n0 + cw * 16 + lrow;
    const unsigned short* src = (wid < 4) ? BgE : BuE;
    bsP = (const char*)src + (long)n * (K * 2) + lcol;
    bDst = ((wid < 4) ? Bgs : Bus) + cw * 16 * BK;
  }

  floatx4 accG[4][NT], accU[4][NT];
  floatx4 zero = {0.f, 0.f, 0.f, 0.f};
#pragma unroll
  for (int i = 0; i < 4; ++i)
#pragma unroll
    for (int j = 0; j < NT; ++j) { accG[i][j] = zero; accU[i][j] = zero; }

  const int ar = lane & 15;
  const int aksw = (((lane >> 4) ^ ((ar >> 1) & 3)) << 3);  // swizzled k-chunk

  auto stage = [&](int p, int k0) {
#pragma unroll
    for (int i = 0; i < 2; ++i)
      gl_lds16(aP[i] + (long)k0 * 2, &As[p * ATILE + (wid * 32 + i * 16) * BK]);
    if constexpr (BN == 128) {
      gl_lds16(bgP + (long)k0 * 2, &Bgs[p * BTILE + (wid * 16) * BK]);
      gl_lds16(buP + (long)k0 * 2, &Bus[p * BTILE + (wid * 16) * BK]);
    } else {
      gl_lds16(bsP + (long)k0 * 2, bDst + p * BTILE);
    }
  };

  stage(0, 0);
  const int NI = K / BK;
  for (int i = 0; i < NI; ++i) {
    __syncthreads();  // vmcnt drained before barrier -> buf[i&1] ready
    if (i + 1 < NI) stage((i + 1) & 1, (i + 1) * BK);
    const unsigned short* Ab = &As[(i & 1) * ATILE];
    const unsigned short* Gb = &Bgs[(i & 1) * BTILE];
    const unsigned short* Ub = &Bus[(i & 1) * BTILE];
    short8 af[4], bgf[NT], buf2[NT];
#pragma unroll
    for (int tm = 0; tm < 4; ++tm)
      af[tm] = *(const short8*)&Ab[(wm * 64 + tm * 16 + ar) * BK + aksw];
#pragma unroll
    for (int tn = 0; tn < NT; ++tn) {
      bgf[tn] = *(const short8*)&Gb[(wn * (BN / 2) + tn * 16 + ar) * BK + aksw];
      buf2[tn] = *(const short8*)&Ub[(wn * (BN / 2) + tn * 16 + ar) * BK + aksw];
    }
#pragma unroll
    for (int tm = 0; tm < 4; ++tm)
#pragma unroll
      for (int tn = 0; tn < NT; ++tn) {
        accG[tm][tn] = __builtin_amdgcn_mfma_f32_16x16x32_bf16(af[tm], bgf[tn], accG[tm][tn], 0, 0, 0);
        accU[tm][tn] = __builtin_amdgcn_mfma_f32_16x16x32_bf16(af[tm], buf2[tn], accU[tm][tn], 0, 0, 0);
      }
  }

#pragma unroll
  for (int tm = 0; tm < 4; ++tm)
#pragma unroll
    for (int tn = 0; tn < NT; ++tn)
#pragma unroll
      for (int r = 0; r < 4; ++r) {
        int row = m0 + wm * 64 + tm * 16 + (lane >> 4) * 4 + r;
        int col = n0 + wn * (BN / 2) + tn * 16 + (lane & 15);
        if (!GATHER || row < Meff) {
          float g = accG[tm][tn][r];
          float u = accU[tm][tn][r];
          float act = g / (1.f + expf(-g)) * u;
          Out[(long)(baseE + row) * N + col] = f2bf(act);
        }
      }
}

// Fused launch (512 threads): blocks [0,128) = shared SwiGLU
// (BM256xBN128: 16bx x 8by); blocks [128,640) = expert SwiGLU
// (BM256xBN64: 8bx x 8by per expert, ~16 active each -> ~128 active).
__global__ __launch_bounds__(512, 2) void swiglu_fused(
    const unsigned short* __restrict__ xb, const unsigned short* __restrict__ sgate,
    const unsigned short* __restrict__ sup, unsigned short* __restrict__ act_s,
    const unsigned short* __restrict__ gup, unsigned short* __restrict__ act_e,
    const int* __restrict__ slot_token, const int* __restrict__ cnt,
    const int* __restrict__ ebase) {
  __shared__ __align__(16) char smem[65536];
  int bid = blockIdx.x;
  if (bid < 128) {
    swiglu_body<false, 128>(smem, bid & 15, bid >> 4, 0, xb, sgate, sup, act_s,
                            nullptr, nullptr, nullptr, SI_DIM, H_DIM, 0);
  } else {
    int b2 = bid - 128;
    int e = b2 >> 6;
    int rem = b2 & 63;  // bx in [0,8), by in [0,8)
    swiglu_body<true, 64>(smem, rem & 7, rem >> 3, e, xb, gup,
                          gup + (long)I_DIM * H_DIM, act_e, slot_token, cnt,
                          ebase, I_DIM, H_DIM, (long)2 * I_DIM * H_DIM);
  }
}

// ---------------------------------------------------------------------------
// Down-proj GEMM body: C = A@B^T. BM=256, BN=128, BK=32, 512 threads
// (8 waves 4m x 2n, wave 64x64): 8 ds_read_b128 -> 16 MFMA per wave-iter.
// MODE 0: shared split-K part 0 -> OutF[row][col] = v (raw fp32)
// MODE 2: shared split-K part 1 -> OutB[row][col] = bf16(v)
// MODE 1: expert -> OutB[(baseE+row)][col] = bf16(v)
// ---------------------------------------------------------------------------
template <int MODE>
__device__ __forceinline__ void down_body(
    char* smem, int bx, int by, int e,
    const unsigned short* __restrict__ A, const unsigned short* __restrict__ B,
    float* __restrict__ OutF, unsigned short* __restrict__ OutB,
    const int* __restrict__ ebase, const int* __restrict__ cnt,
    int N, int Kstride, int kbeg, int kcnt, long estrideB) {
  constexpr int BM = 256, BN = 128, BK = 32;
  constexpr int ATILE = BM * BK;
  constexpr int BTILE = BN * BK;
  const int tid = threadIdx.x;
  const int lane = tid & 63;
  const int wid = tid >> 6;
  const int wm = wid & 3;
  const int wn = wid >> 2;
  const int m0 = by * BM;
  const int n0 = bx * BN;
  int Meff = 0, baseE = 0;
  if (MODE == 1) {
    Meff = cnt[e];
    if (m0 >= Meff) return;
    baseE = ebase[e];
  }
  const unsigned short* BE = B + (long)e * estrideB;

  unsigned short* As = (unsigned short*)smem;  // [2][256*32]
  unsigned short* Bs = As + 2 * ATILE;         // [2][128*32]

  const int lrow = lane >> 2;
  const int lcol = (((lane & 3) ^ ((lrow >> 1) & 3)) << 4);

  const char* aP[2];
#pragma unroll
  for (int i = 0; i < 2; ++i) {
    int m = m0 + wid * 32 + i * 16 + lrow;
    long arow;
    if (MODE == 1) {
      int mm = (m < Meff - 1) ? m : (Meff - 1);
      arow = baseE + mm;
    } else {
      arow = m;
    }
    aP[i] = (const char*)A + arow * (long)(Kstride * 2) + (long)kbeg * 2 + lcol;
  }
  int nb = n0 + wid * 16 + lrow;
  const char* bP = (const char*)BE + (long)nb * (Kstride * 2) + (long)kbeg * 2 + lcol;

  floatx4 acc[4][4];
  floatx4 zero = {0.f, 0.f, 0.f, 0.f};
#pragma unroll
  for (int i = 0; i < 4; ++i)
#pragma unroll
    for (int j = 0; j < 4; ++j) acc[i][j] = zero;

  const int ar = lane & 15;
  const int aksw = (((lane >> 4) ^ ((ar >> 1) & 3)) << 3);

  auto stage = [&](int p, int k0) {
#pragma unroll
    for (int i = 0; i < 2; ++i)
      gl_lds16(aP[i] + (long)k0 * 2, &As[p * ATILE + (wid * 32 + i * 16) * BK]);
    gl_lds16(bP + (long)k0 * 2, &Bs[p * BTILE + (wid * 16) * BK]);
  };

  stage(0, 0);
  const int NI = kcnt / BK;
  for (int i = 0; i < NI; ++i) {
    __syncthreads();
    if (i + 1 < NI) stage((i + 1) & 1, (i + 1) * BK);
    const unsigned short* Ab = &As[(i & 1) * ATILE];
    const unsigned short* Bb = &Bs[(i & 1) * BTILE];
    short8 af[4], bf[4];
#pragma unroll
    for (int tm = 0; tm < 4; ++tm)
      af[tm] = *(const short8*)&Ab[(wm * 64 + tm * 16 + ar) * BK + aksw];
#pragma unroll
    for (int tn = 0; tn < 4; ++tn)
      bf[tn] = *(const short8*)&Bb[(wn * 64 + tn * 16 + ar) * BK + aksw];
#pragma unroll
    for (int tm = 0; tm < 4; ++tm)
#pragma unroll
      for (int tn = 0; tn < 4; ++tn)
        acc[tm][tn] = __builtin_amdgcn_mfma_f32_16x16x32_bf16(af[tm], bf[tn], acc[tm][tn], 0, 0, 0);
  }

#pragma unroll
  for (int tm = 0; tm < 4; ++tm)
#pragma unroll
    for (int r = 0; r < 4; ++r) {
      int row = m0 + wm * 64 + tm * 16 + (lane >> 4) * 4 + r;
#pragma unroll
      for (int tn = 0; tn < 4; ++tn) {
        int col = n0 + wn * 64 + tn * 16 + (lane & 15);
        float v = acc[tm][tn][r];
        if (MODE == 0) {
          OutF[(long)row * N + col] = v;
        } else if (MODE == 2) {
          OutB[(long)row * N + col] = f2bf(v);
        } else if (row < Meff) {
          OutB[(long)(baseE + row) * N + col] = f2bf(v);
        }
      }
    }
}

// Fused launch (512 threads): [0,128) shared down split-K
// (ks = bid>>6; 8bx x 8by): ks0 -> out raw fp32, ks1 -> spart bf16;
// [128,640) expert down (8bx x 8by per expert, ~16 active -> 128 active).
__global__ __launch_bounds__(512, 2) void down_fused(
    const unsigned short* __restrict__ act_s, const unsigned short* __restrict__ sdown,
    float* __restrict__ out, unsigned short* __restrict__ spart,
    const unsigned short* __restrict__ act_e, const unsigned short* __restrict__ downw,
    unsigned short* __restrict__ eout, const int* __restrict__ ebase,
    const int* __restrict__ cnt) {
  __shared__ __align__(16) char smem[49152];
  int bid = blockIdx.x;
  if (bid < 128) {
    int ks = bid >> 6;
    int rem = bid & 63;  // bx in [0,8), by in [0,8)
    if (ks == 0)
      down_body<0>(smem, rem & 7, rem >> 3, 0, act_s, sdown, out, nullptr,
                   nullptr, nullptr, H_DIM, SI_DIM, 0, 1024, 0);
    else
      down_body<2>(smem, rem & 7, rem >> 3, 0, act_s, sdown, nullptr, spart,
                   nullptr, nullptr, H_DIM, SI_DIM, 1024, 1024, 0);
  } else {
    int b2 = bid - 128;
    int e = b2 >> 6;
    int rem = b2 & 63;  // bx in [0,8), by in [0,8)
    down_body<1>(smem, rem & 7, rem >> 3, e, act_e, downw, nullptr, eout,
                 ebase, cnt, H_DIM, I_DIM, 0, I_DIM, (long)H_DIM * I_DIM);
  }
}

// ---------------------------------------------------------------------------
// Combine: out[t][h] = sg[t]*(p0 + p1) + w0*eout[s0][h] + w1*eout[s1][h].
// p0 = raw fp32 in out, p1 = bf16 in spart. One block per token.
// ---------------------------------------------------------------------------
__global__ __launch_bounds__(256) void combine_kernel(
    float* __restrict__ out, const unsigned short* __restrict__ spart,
    const unsigned short* __restrict__ eout, const float* __restrict__ sg,
    const float2* __restrict__ w01, const int* __restrict__ tok_slot) {
  int t = blockIdx.x;
  int c = threadIdx.x;  // 256 threads x 4 elems = 1024
  float sgr = sg[t];
  float2 wr = w01[t];
  int s0 = tok_slot[2 * t];
  int s1 = tok_slot[2 * t + 1];
  ushort4 p1 = ((const ushort4*)(spart + (long)t * H_DIM))[c];
  ushort4 e0 = ((const ushort4*)(eout + (long)s0 * H_DIM))[c];
  ushort4 e1 = ((const ushort4*)(eout + (long)s1 * H_DIM))[c];
  float4* op = &((float4*)(out + (long)t * H_DIM))[c];
  float4 o = *op;
  o.x = sgr * (o.x + bf2f(p1.x)) + wr.x * bf2f(e0.x) + wr.y * bf2f(e1.x);
  o.y = sgr * (o.y + bf2f(p1.y)) + wr.x * bf2f(e0.y) + wr.y * bf2f(e1.y);
  o.z = sgr * (o.z + bf2f(p1.z)) + wr.x * bf2f(e0.z) + wr.y * bf2f(e1.z);
  o.w = sgr * (o.w + bf2f(p1.w)) + wr.x * bf2f(e0.w) + wr.y * bf2f(e1.w);
  *op = o;
}

// ---------------------------------------------------------------------------
// Workspace map (bytes), total ~63.0 MB (ws proven >= 67.25 MB in round 1):
//   0         xb       bf16[2048][1024]     (reused as spart by down split-K)
//   4194304   gup_b    bf16[8][1024][1024]
//  20971520   down_b   bf16[8][1024][512]
//  29360128   sgate_b  bf16[2048][1024]
//  33554432   sup_b    bf16[2048][1024]
//  37748736   sdown_b  bf16[1024][2048]
//  41943040   act_s    bf16[2048][2048]
//  50331648   act_e    bf16[4096][512]
//  54525952   eout     bf16[4096][1024]
//  62914560   sg / top2 / w01 / cnt / ebase / slot_token / tok_slot
// ---------------------------------------------------------------------------
extern "C" void kernel_launch(void* const* d_in, const int* in_sizes, int n_in,
                              void* d_out, int out_size, void* d_ws, size_t ws_size,
                              hipStream_t stream) {
  const float* x = (const float*)d_in[0];
  const float* rw = (const float*)d_in[1];
  const float* gup = (const float*)d_in[2];
  const float* dwn = (const float*)d_in[3];
  const float* sgw = (const float*)d_in[4];
  const float* suw = (const float*)d_in[5];
  const float* sdw = (const float*)d_in[6];
  const float* segw = (const float*)d_in[7];
  float* out = (float*)d_out;

  char* w = (char*)d_ws;
  unsigned short* xb = (unsigned short*)(w + 0);
  unsigned short* gup_b = (unsigned short*)(w + 4194304L);
  unsigned short* down_b = (unsigned short*)(w + 20971520L);
  unsigned short* sgate_b = (unsigned short*)(w + 29360128L);
  unsigned short* sup_b = (unsigned short*)(w + 33554432L);
  unsigned short* sdown_b = (unsigned short*)(w + 37748736L);
  unsigned short* act_s = (unsigned short*)(w + 41943040L);
  unsigned short* act_e = (unsigned short*)(w + 50331648L);
  unsigned short* eout = (unsigned short*)(w + 54525952L);
  float* sg = (float*)(w + 62914560L);
  int* top2 = (int*)(w + 62922752L);
  float2* w01 = (float2*)(w + 62930944L);
  int* cnt = (int*)(w + 62947328L);
  int* ebase = (int*)(w + 62947584L);
  int* slot_token = (int*)(w + 62947840L);
  int* tok_slot = (int*)(w + 62964224L);
  unsigned short* spart = xb;  // xb dead after swiglu_fused; reuse for split-K partial

  // router (512 blocks, first) + cast (20480 blocks) in one launch
  cast_router<<<20992, 256, 0, stream>>>(x, rw, segw, gup, dwn, sgw, suw, sdw,
                                         xb, gup_b, down_b, sgate_b, sup_b,
                                         sdown_b, top2, w01, sg);
  build_lists<<<E_NUM, 256, 0, stream>>>(top2, cnt, ebase, slot_token, tok_slot);
  // fused shared+expert SwiGLU: 512-thread blocks, ~256 active = 1 per CU
  swiglu_fused<<<640, 512, 0, stream>>>(xb, sgate_b, sup_b, act_s, gup_b,
                                        act_e, slot_token, cnt, ebase);
  // fused shared (split-K x2) + expert down-proj: ~256 active = 1 per CU
  down_fused<<<640, 512, 0, stream>>>(act_s, sdown_b, out, spart, act_e,
                                      down_b, eout, ebase, cnt);
  // out = sg*(p0+p1) + w0*eout[s0] + w1*eout[s1]
  combine_kernel<<<T_TOK, 256, 0, stream>>>(out, spart, eout, sg, w01, tok_slot);
}

// Round 9
// 209.337 us; speedup vs baseline: 1.0100x; 1.0100x over previous
//
#include <hip/hip_runtime.h>

// Problem constants (B=2,S=1024 -> T=2048; H=1024, I=512, SI=2048, E=8, TOPK=2)
#define T_TOK 2048
#define H_DIM 1024
#define I_DIM 512
#define SI_DIM 2048
#define E_NUM 8
#define NSLOT 4096  // total expert slots: exactly 2 per token

typedef __attribute__((ext_vector_type(8))) short short8;   // 8 x bf16 (4 VGPRs)
typedef __attribute__((ext_vector_type(4))) float floatx4;  // MFMA C/D

// fp32 -> bf16 round-to-nearest-even
__device__ inline unsigned short f2bf(float f) {
  unsigned u = __builtin_bit_cast(unsigned, f);
  u = (u + 0x7FFFu + ((u >> 16) & 1u)) >> 16;
  return (unsigned short)u;
}
__device__ inline float bf2f(unsigned short u) {
  return __builtin_bit_cast(float, (unsigned)u << 16);
}

// async global->LDS, 16B per lane; LDS dest = wave-uniform base + lane*16
__device__ inline void gl_lds16(const void* g, void* l) {
  __builtin_amdgcn_global_load_lds(
      (const __attribute__((address_space(1))) unsigned int*)g,
      (__attribute__((address_space(3))) unsigned int*)l, 16, 0, 0);
}

// ---------------------------------------------------------------------------
// Fused cast + router. Blocks [0,512): router (latency-bound, dispatched
// first so it overlaps the BW-bound cast flood). Blocks [512,20992): cast.
// ---------------------------------------------------------------------------
__global__ __launch_bounds__(256) void cast_router(
    const float* __restrict__ x, const float* __restrict__ rw,
    const float* __restrict__ segw,
    const float* __restrict__ s1, const float* __restrict__ s2,
    const float* __restrict__ s3, const float* __restrict__ s4,
    const float* __restrict__ s5,
    unsigned short* __restrict__ d0, unsigned short* __restrict__ d1,
    unsigned short* __restrict__ d2, unsigned short* __restrict__ d3,
    unsigned short* __restrict__ d4, unsigned short* __restrict__ d5,
    int* __restrict__ top2, float2* __restrict__ w01, float* __restrict__ sg) {
  const int bid = blockIdx.x;
  if (bid < 512) {
    // ---- router: one wave per token, fp32 logits (matches ref numerics) ----
    int t = bid * 4 + (threadIdx.x >> 6);
    int lane = threadIdx.x & 63;
    const float* xt = x + (long)t * H_DIM;
    float xv[16];
#pragma unroll
    for (int j = 0; j < 16; ++j) xv[j] = xt[j * 64 + lane];
    float dots[9];
#pragma unroll
    for (int e = 0; e < 8; ++e) {
      const float* w = rw + e * H_DIM;
      float s = 0.f;
#pragma unroll
      for (int j = 0; j < 16; ++j) s += xv[j] * w[j * 64 + lane];
      dots[e] = s;
    }
    {
      float s = 0.f;
#pragma unroll
      for (int j = 0; j < 16; ++j) s += xv[j] * segw[j * 64 + lane];
      dots[8] = s;
    }
#pragma unroll
    for (int off = 32; off > 0; off >>= 1) {
#pragma unroll
      for (int e = 0; e < 9; ++e) dots[e] += __shfl_xor(dots[e], off, 64);
    }
    if (lane == 0) {
      int e0 = 0;
      for (int e = 1; e < 8; ++e)
        if (dots[e] > dots[e0]) e0 = e;
      int e1 = (e0 == 0) ? 1 : 0;
      for (int e = 0; e < 8; ++e)
        if (e != e0 && dots[e] > dots[e1]) e1 = e;
      float p1 = expf(dots[e1] - dots[e0]);
      top2[t] = e0 | (e1 << 8);
      w01[t] = make_float2(1.f / (1.f + p1), p1 / (1.f + p1));
      sg[t] = 1.f / (1.f + expf(-dots[8]));
    }
  } else {
    // ---- cast: 6 fp32 segments -> bf16, 4 elems/thread ----
    long g = (long)(bid - 512) * 256 + threadIdx.x;
    const float* s;
    unsigned short* d;
    long off;
    if (g < 524288L)       { s = x;  d = d0; off = g; }            // x
    else if (g < 2621440L) { s = s1; d = d1; off = g - 524288L; }  // gate_up
    else if (g < 3670016L) { s = s2; d = d2; off = g - 2621440L; } // down
    else if (g < 4194304L) { s = s3; d = d3; off = g - 3670016L; } // shared_gate
    else if (g < 4718592L) { s = s4; d = d4; off = g - 4194304L; } // shared_up
    else                   { s = s5; d = d5; off = g - 4718592L; } // shared_down
    float4 v = ((const float4*)s)[off];
    ushort4 o;
    o.x = f2bf(v.x); o.y = f2bf(v.y); o.z = f2bf(v.z); o.w = f2bf(v.w);
    ((ushort4*)d)[off] = o;
  }
}

// ---------------------------------------------------------------------------
// Router phase 2: one block per expert; block-wide scan -> compact slot list
// (global base = #assignments to experts < e) + tok_slot back-pointers.
// ---------------------------------------------------------------------------
__global__ __launch_bounds__(256) void build_lists(
    const int* __restrict__ top2, int* __restrict__ cnt, int* __restrict__ ebase,
    int* __restrict__ slot_token, int* __restrict__ tok_slot) {
  const int e = blockIdx.x;
  const int tid = threadIdx.x;
  const int lane = tid & 63, wid = tid >> 6;
  __shared__ int wsum[4], wbelow[4];
  const int base_t = tid * 8;  // 2048 / 256
  int mk[8], kk[8];
  int c = 0, below = 0;
#pragma unroll
  for (int j = 0; j < 8; ++j) {
    int p = top2[base_t + j];
    int e0 = p & 0xFF, e1 = (p >> 8) & 0xFF;
    below += (e0 < e) + (e1 < e);
    int m = 0, k = 0;
    if (e0 == e) { m = 1; k = 0; }
    else if (e1 == e) { m = 1; k = 1; }
    mk[j] = m; kk[j] = k;
    c += m;
  }
  int inc = c;
#pragma unroll
  for (int off = 1; off < 64; off <<= 1) {
    int n = __shfl_up(inc, off, 64);
    if (lane >= off) inc += n;
  }
  int bsum = below;
#pragma unroll
  for (int off = 32; off > 0; off >>= 1) bsum += __shfl_xor(bsum, off, 64);
  if (lane == 63) wsum[wid] = inc;
  if (lane == 0) wbelow[wid] = bsum;
  __syncthreads();
  int woff = 0;
#pragma unroll
  for (int i = 0; i < 4; ++i)
    if (i < wid) woff += wsum[i];
  int baseE = wbelow[0] + wbelow[1] + wbelow[2] + wbelow[3];
  int pos = baseE + woff + inc - c;
#pragma unroll
  for (int j = 0; j < 8; ++j) {
    if (mk[j]) {
      slot_token[pos] = base_t + j;
      tok_slot[2 * (base_t + j) + kk[j]] = pos;
      pos++;
    }
  }
  if (tid == 255) cnt[e] = woff + inc;
  if (tid == 0) ebase[e] = baseE;
}

// ---------------------------------------------------------------------------
// Fused SwiGLU GEMM body: act = silu(A@Bg^T)*(A@Bu^T), bf16, fp32 acc.
// BM=128, BK=32, 256 threads = 4 waves (2m x 2n); wave tile 64 x (BN/2),
// both G and U. BN=128: 12 ds_read_b128 -> 32 MFMA per wave-iter.
// Double-buffered LDS (1 barrier/iter) + XOR bank swizzle (0 conflicts).
// Grid balanced so active blocks == 2 per CU, single residency generation,
// 2 independent blocks/CU so one computes while the other drains vmcnt.
// ---------------------------------------------------------------------------
template <bool GATHER, int BN>
__device__ __forceinline__ void swiglu_body(
    char* smem, int bx, int by, int e,
    const unsigned short* __restrict__ A, const unsigned short* __restrict__ Bg,
    const unsigned short* __restrict__ Bu, unsigned short* __restrict__ Out,
    const int* __restrict__ slot_token, const int* __restrict__ cnt,
    const int* __restrict__ ebase, int N, int K, long estrideB) {
  constexpr int BM = 128, BK = 32;
  constexpr int NT = BN / 32;      // n-tiles of 16 per wave
  constexpr int BCH = BN / 64;     // B chunks staged per wave (1 or 2)
  constexpr int ATILE = BM * BK;   // ushorts
  constexpr int BTILE = BN * BK;
  const int tid = threadIdx.x;
  const int lane = tid & 63;
  const int wid = tid >> 6;  // 0..3
  const int wm = wid & 1;    // 2 m-positions (64 rows each)
  const int wn = wid >> 1;   // 2 n-positions (BN/2 cols each)
  const int m0 = by * BM;
  const int n0 = bx * BN;
  int Meff = 0, baseE = 0;
  if (GATHER) {
    Meff = cnt[e];
    if (m0 >= Meff) return;
    baseE = ebase[e];
  }
  const unsigned short* BgE = Bg + (long)e * estrideB;
  const unsigned short* BuE = Bu + (long)e * estrideB;

  unsigned short* As = (unsigned short*)smem;  // [2][128*32]
  unsigned short* Bgs = As + 2 * ATILE;        // [2][BN*32]
  unsigned short* Bus = Bgs + 2 * BTILE;       // [2][BN*32]

  const int lrow = lane >> 2;  // 16 rows / 1KB chunk
  const int lcol = (((lane & 3) ^ ((lrow >> 1) & 3)) << 4);  // swizzled 16B col

  // A staging: 128 rows = 4 waves x 2 chunks of 16 rows
  const char* aP[2];
#pragma unroll
  for (int i = 0; i < 2; ++i) {
    int m = m0 + wid * 32 + i * 16 + lrow;
    long row;
    if (GATHER) {
      int mm = (m < Meff - 1) ? m : (Meff - 1);  // clamp tail to valid slot
      row = slot_token[baseE + mm];
    } else {
      row = m;
    }
    aP[i] = (const char*)A + row * (long)(K * 2) + lcol;
  }
  // B staging: BN/16 chunks over 4 waves -> BCH per wave for each of G,U
  const char* bgP[BCH];
  const char* buP[BCH];
#pragma unroll
  for (int i = 0; i < BCH; ++i) {
    int n = n0 + wid * (16 * BCH) + i * 16 + lrow;
    bgP[i] = (const char*)BgE + (long)n * (K * 2) + lcol;
    buP[i] = (const char*)BuE + (long)n * (K * 2) + lcol;
  }

  floatx4 accG[4][NT], accU[4][NT];
  floatx4 zero = {0.f, 0.f, 0.f, 0.f};
#pragma unroll
  for (int i = 0; i < 4; ++i)
#pragma unroll
    for (int j = 0; j < NT; ++j) { accG[i][j] = zero; accU[i][j] = zero; }

  const int ar = lane & 15;
  const int aksw = (((lane >> 4) ^ ((ar >> 1) & 3)) << 3);  // swizzled k-chunk

  auto stage = [&](int p, int k0) {
#pragma unroll
    for (int i = 0; i < 2; ++i)
      gl_lds16(aP[i] + (long)k0 * 2, &As[p * ATILE + (wid * 32 + i * 16) * BK]);
#pragma unroll
    for (int i = 0; i < BCH; ++i) {
      gl_lds16(bgP[i] + (long)k0 * 2,
               &Bgs[p * BTILE + (wid * 16 * BCH + i * 16) * BK]);
      gl_lds16(buP[i] + (long)k0 * 2,
               &Bus[p * BTILE + (wid * 16 * BCH + i * 16) * BK]);
    }
  };

  stage(0, 0);
  const int NI = K / BK;
  for (int i = 0; i < NI; ++i) {
    __syncthreads();  // vmcnt drained before barrier -> buf[i&1] ready
    if (i + 1 < NI) stage((i + 1) & 1, (i + 1) * BK);
    const unsigned short* Ab = &As[(i & 1) * ATILE];
    const unsigned short* Gb = &Bgs[(i & 1) * BTILE];
    const unsigned short* Ub = &Bus[(i & 1) * BTILE];
    short8 af[4], bgf[NT], buf2[NT];
#pragma unroll
    for (int tm = 0; tm < 4; ++tm)
      af[tm] = *(const short8*)&Ab[(wm * 64 + tm * 16 + ar) * BK + aksw];
#pragma unroll
    for (int tn = 0; tn < NT; ++tn) {
      bgf[tn] = *(const short8*)&Gb[(wn * (BN / 2) + tn * 16 + ar) * BK + aksw];
      buf2[tn] = *(const short8*)&Ub[(wn * (BN / 2) + tn * 16 + ar) * BK + aksw];
    }
#pragma unroll
    for (int tm = 0; tm < 4; ++tm)
#pragma unroll
      for (int tn = 0; tn < NT; ++tn) {
        accG[tm][tn] = __builtin_amdgcn_mfma_f32_16x16x32_bf16(af[tm], bgf[tn], accG[tm][tn], 0, 0, 0);
        accU[tm][tn] = __builtin_amdgcn_mfma_f32_16x16x32_bf16(af[tm], buf2[tn], accU[tm][tn], 0, 0, 0);
      }
  }

#pragma unroll
  for (int tm = 0; tm < 4; ++tm)
#pragma unroll
    for (int tn = 0; tn < NT; ++tn)
#pragma unroll
      for (int r = 0; r < 4; ++r) {
        int row = m0 + wm * 64 + tm * 16 + (lane >> 4) * 4 + r;
        int col = n0 + wn * (BN / 2) + tn * 16 + (lane & 15);
        if (!GATHER || row < Meff) {
          float g = accG[tm][tn][r];
          float u = accU[tm][tn][r];
          float act = g / (1.f + expf(-g)) * u;
          Out[(long)(baseE + row) * N + col] = f2bf(act);
        }
      }
}

// Fused launch (256 threads): blocks [0,256) = shared SwiGLU
// (BM128xBN128: 16bx x 16by); blocks [256,1280) = expert SwiGLU
// (BM128xBN64: 8bx x 16by per expert; ~32 active each -> ~256 active).
// Active total ~512 = 2 blocks/CU, one generation.
__global__ __launch_bounds__(256, 2) void swiglu_fused(
    const unsigned short* __restrict__ xb, const unsigned short* __restrict__ sgate,
    const unsigned short* __restrict__ sup, unsigned short* __restrict__ act_s,
    const unsigned short* __restrict__ gup, unsigned short* __restrict__ act_e,
    const int* __restrict__ slot_token, const int* __restrict__ cnt,
    const int* __restrict__ ebase) {
  __shared__ __align__(16) char smem[49152];
  int bid = blockIdx.x;
  if (bid < 256) {
    swiglu_body<false, 128>(smem, bid & 15, bid >> 4, 0, xb, sgate, sup, act_s,
                            nullptr, nullptr, nullptr, SI_DIM, H_DIM, 0);
  } else {
    int b2 = bid - 256;
    int e = b2 >> 7;
    int rem = b2 & 127;  // bx in [0,8), by in [0,16)
    swiglu_body<true, 64>(smem, rem & 7, rem >> 3, e, xb, gup,
                          gup + (long)I_DIM * H_DIM, act_e, slot_token, cnt,
                          ebase, I_DIM, H_DIM, (long)2 * I_DIM * H_DIM);
  }
}

// ---------------------------------------------------------------------------
// Down-proj GEMM body: C = A@B^T. BM=128, BN=128, BK=32, 256 threads
// (4 waves 2m x 2n, wave 64x64): 8 ds_read_b128 -> 16 MFMA per wave-iter.
// MODE 0: shared split-K part 0 -> OutF[row][col] = v (raw fp32)
// MODE 2: shared split-K part 1 -> OutB[row][col] = bf16(v)
// MODE 1: expert -> OutB[(baseE+row)][col] = bf16(v)
// ---------------------------------------------------------------------------
template <int MODE>
__device__ __forceinline__ void down_body(
    char* smem, int bx, int by, int e,
    const unsigned short* __restrict__ A, const unsigned short* __restrict__ B,
    float* __restrict__ OutF, unsigned short* __restrict__ OutB,
    const int* __restrict__ ebase, const int* __restrict__ cnt,
    int N, int Kstride, int kbeg, int kcnt, long estrideB) {
  constexpr int BM = 128, BN = 128, BK = 32;
  constexpr int ATILE = BM * BK;
  constexpr int BTILE = BN * BK;
  const int tid = threadIdx.x;
  const int lane = tid & 63;
  const int wid = tid >> 6;
  const int wm = wid & 1;
  const int wn = wid >> 1;
  const int m0 = by * BM;
  const int n0 = bx * BN;
  int Meff = 0, baseE = 0;
  if (MODE == 1) {
    Meff = cnt[e];
    if (m0 >= Meff) return;
    baseE = ebase[e];
  }
  const unsigned short* BE = B + (long)e * estrideB;

  unsigned short* As = (unsigned short*)smem;  // [2][128*32]
  unsigned short* Bs = As + 2 * ATILE;         // [2][128*32]

  const int lrow = lane >> 2;
  const int lcol = (((lane & 3) ^ ((lrow >> 1) & 3)) << 4);

  const char* aP[2];
  const char* bP[2];
#pragma unroll
  for (int i = 0; i < 2; ++i) {
    int m = m0 + wid * 32 + i * 16 + lrow;
    long arow;
    if (MODE == 1) {
      int mm = (m < Meff - 1) ? m : (Meff - 1);
      arow = baseE + mm;
    } else {
      arow = m;
    }
    aP[i] = (const char*)A + arow * (long)(Kstride * 2) + (long)kbeg * 2 + lcol;
    int n = n0 + wid * 32 + i * 16 + lrow;
    bP[i] = (const char*)BE + (long)n * (Kstride * 2) + (long)kbeg * 2 + lcol;
  }

  floatx4 acc[4][4];
  floatx4 zero = {0.f, 0.f, 0.f, 0.f};
#pragma unroll
  for (int i = 0; i < 4; ++i)
#pragma unroll
    for (int j = 0; j < 4; ++j) acc[i][j] = zero;

  const int ar = lane & 15;
  const int aksw = (((lane >> 4) ^ ((ar >> 1) & 3)) << 3);

  auto stage = [&](int p, int k0) {
#pragma unroll
    for (int i = 0; i < 2; ++i) {
      gl_lds16(aP[i] + (long)k0 * 2, &As[p * ATILE + (wid * 32 + i * 16) * BK]);
      gl_lds16(bP[i] + (long)k0 * 2, &Bs[p * BTILE + (wid * 32 + i * 16) * BK]);
    }
  };

  stage(0, 0);
  const int NI = kcnt / BK;
  for (int i = 0; i < NI; ++i) {
    __syncthreads();
    if (i + 1 < NI) stage((i + 1) & 1, (i + 1) * BK);
    const unsigned short* Ab = &As[(i & 1) * ATILE];
    const unsigned short* Bb = &Bs[(i & 1) * BTILE];
    short8 af[4], bf[4];
#pragma unroll
    for (int tm = 0; tm < 4; ++tm)
      af[tm] = *(const short8*)&Ab[(wm * 64 + tm * 16 + ar) * BK + aksw];
#pragma unroll
    for (int tn = 0; tn < 4; ++tn)
      bf[tn] = *(const short8*)&Bb[(wn * 64 + tn * 16 + ar) * BK + aksw];
#pragma unroll
    for (int tm = 0; tm < 4; ++tm)
#pragma unroll
      for (int tn = 0; tn < 4; ++tn)
        acc[tm][tn] = __builtin_amdgcn_mfma_f32_16x16x32_bf16(af[tm], bf[tn], acc[tm][tn], 0, 0, 0);
  }

#pragma unroll
  for (int tm = 0; tm < 4; ++tm)
#pragma unroll
    for (int r = 0; r < 4; ++r) {
      int row = m0 + wm * 64 + tm * 16 + (lane >> 4) * 4 + r;
#pragma unroll
      for (int tn = 0; tn < 4; ++tn) {
        int col = n0 + wn * 64 + tn * 16 + (lane & 15);
        float v = acc[tm][tn][r];
        if (MODE == 0) {
          OutF[(long)row * N + col] = v;
        } else if (MODE == 2) {
          OutB[(long)row * N + col] = f2bf(v);
        } else if (row < Meff) {
          OutB[(long)(baseE + row) * N + col] = f2bf(v);
        }
      }
    }
}

// Fused launch (256 threads): [0,256) shared down split-K
// (ks = bid>>7; 8bx x 16by): ks0 -> out raw fp32, ks1 -> spart bf16;
// [256,1280) expert down (8bx x 16by per expert; ~32 active -> ~256 active).
// Active total ~512 = 2 blocks/CU.
__global__ __launch_bounds__(256, 2) void down_fused(
    const unsigned short* __restrict__ act_s, const unsigned short* __restrict__ sdown,
    float* __restrict__ out, unsigned short* __restrict__ spart,
    const unsigned short* __restrict__ act_e, const unsigned short* __restrict__ downw,
    unsigned short* __restrict__ eout, const int* __restrict__ ebase,
    const int* __restrict__ cnt) {
  __shared__ __align__(16) char smem[32768];
  int bid = blockIdx.x;
  if (bid < 256) {
    int ks = bid >> 7;
    int rem = bid & 127;  // bx in [0,8), by in [0,16)
    if (ks == 0)
      down_body<0>(smem, rem & 7, rem >> 3, 0, act_s, sdown, out, nullptr,
                   nullptr, nullptr, H_DIM, SI_DIM, 0, 1024, 0);
    else
      down_body<2>(smem, rem & 7, rem >> 3, 0, act_s, sdown, nullptr, spart,
                   nullptr, nullptr, H_DIM, SI_DIM, 1024, 1024, 0);
  } else {
    int b2 = bid - 256;
    int e = b2 >> 7;
    int rem = b2 & 127;  // bx in [0,8), by in [0,16)
    down_body<1>(smem, rem & 7, rem >> 3, e, act_e, downw, nullptr, eout,
                 ebase, cnt, H_DIM, I_DIM, 0, I_DIM, (long)H_DIM * I_DIM);
  }
}

// ---------------------------------------------------------------------------
// Combine: out[t][h] = sg[t]*(p0 + p1) + w0*eout[s0][h] + w1*eout[s1][h].
// p0 = raw fp32 in out, p1 = bf16 in spart. One block per token.
// ---------------------------------------------------------------------------
__global__ __launch_bounds__(256) void combine_kernel(
    float* __restrict__ out, const unsigned short* __restrict__ spart,
    const unsigned short* __restrict__ eout, const float* __restrict__ sg,
    const float2* __restrict__ w01, const int* __restrict__ tok_slot) {
  int t = blockIdx.x;
  int c = threadIdx.x;  // 256 threads x 4 elems = 1024
  float sgr = sg[t];
  float2 wr = w01[t];
  int s0 = tok_slot[2 * t];
  int s1 = tok_slot[2 * t + 1];
  ushort4 p1 = ((const ushort4*)(spart + (long)t * H_DIM))[c];
  ushort4 e0 = ((const ushort4*)(eout + (long)s0 * H_DIM))[c];
  ushort4 e1 = ((const ushort4*)(eout + (long)s1 * H_DIM))[c];
  float4* op = &((float4*)(out + (long)t * H_DIM))[c];
  float4 o = *op;
  o.x = sgr * (o.x + bf2f(p1.x)) + wr.x * bf2f(e0.x) + wr.y * bf2f(e1.x);
  o.y = sgr * (o.y + bf2f(p1.y)) + wr.x * bf2f(e0.y) + wr.y * bf2f(e1.y);
  o.z = sgr * (o.z + bf2f(p1.z)) + wr.x * bf2f(e0.z) + wr.y * bf2f(e1.z);
  o.w = sgr * (o.w + bf2f(p1.w)) + wr.x * bf2f(e0.w) + wr.y * bf2f(e1.w);
  *op = o;
}

// ---------------------------------------------------------------------------
// Workspace map (bytes), total ~63.0 MB (ws proven >= 67.25 MB in round 1):
//   0         xb       bf16[2048][1024]     (reused as spart by down split-K)
//   4194304   gup_b    bf16[8][1024][1024]
//  20971520   down_b   bf16[8][1024][512]
//  29360128   sgate_b  bf16[2048][1024]
//  33554432   sup_b    bf16[2048][1024]
//  37748736   sdown_b  bf16[1024][2048]
//  41943040   act_s    bf16[2048][2048]
//  50331648   act_e    bf16[4096][512]
//  54525952   eout     bf16[4096][1024]
//  62914560   sg / top2 / w01 / cnt / ebase / slot_token / tok_slot
// ---------------------------------------------------------------------------
extern "C" void kernel_launch(void* const* d_in, const int* in_sizes, int n_in,
                              void* d_out, int out_size, void* d_ws, size_t ws_size,
                              hipStream_t stream) {
  const float* x = (const float*)d_in[0];
  const float* rw = (const float*)d_in[1];
  const float* gup = (const float*)d_in[2];
  const float* dwn = (const float*)d_in[3];
  const float* sgw = (const float*)d_in[4];
  const float* suw = (const float*)d_in[5];
  const float* sdw = (const float*)d_in[6];
  const float* segw = (const float*)d_in[7];
  float* out = (float*)d_out;

  char* w = (char*)d_ws;
  unsigned short* xb = (unsigned short*)(w + 0);
  unsigned short* gup_b = (unsigned short*)(w + 4194304L);
  unsigned short* down_b = (unsigned short*)(w + 20971520L);
  unsigned short* sgate_b = (unsigned short*)(w + 29360128L);
  unsigned short* sup_b = (unsigned short*)(w + 33554432L);
  unsigned short* sdown_b = (unsigned short*)(w + 37748736L);
  unsigned short* act_s = (unsigned short*)(w + 41943040L);
  unsigned short* act_e = (unsigned short*)(w + 50331648L);
  unsigned short* eout = (unsigned short*)(w + 54525952L);
  float* sg = (float*)(w + 62914560L);
  int* top2 = (int*)(w + 62922752L);
  float2* w01 = (float2*)(w + 62930944L);
  int* cnt = (int*)(w + 62947328L);
  int* ebase = (int*)(w + 62947584L);
  int* slot_token = (int*)(w + 62947840L);
  int* tok_slot = (int*)(w + 62964224L);
  unsigned short* spart = xb;  // xb dead after swiglu_fused; reuse for split-K partial

  // router (512 blocks, first) + cast (20480 blocks) in one launch
  cast_router<<<20992, 256, 0, stream>>>(x, rw, segw, gup, dwn, sgw, suw, sdw,
                                         xb, gup_b, down_b, sgate_b, sup_b,
                                         sdown_b, top2, w01, sg);
  build_lists<<<E_NUM, 256, 0, stream>>>(top2, cnt, ebase, slot_token, tok_slot);
  // fused shared+expert SwiGLU: ~512 active 256-thread blocks = 2 per CU
  swiglu_fused<<<1280, 256, 0, stream>>>(xb, sgate_b, sup_b, act_s, gup_b,
                                         act_e, slot_token, cnt, ebase);
  // fused shared (split-K x2) + expert down-proj: ~512 active = 2 per CU
  down_fused<<<1280, 256, 0, stream>>>(act_s, sdown_b, out, spart, act_e,
                                       down_b, eout, ebase, cnt);
  // out = sg*(p0+p1) + w0*eout[s0] + w1*eout[s1]
  combine_kernel<<<T_TOK, 256, 0, stream>>>(out, spart, eout, sg, w01, tok_slot);
}

// Round 10
// 206.283 us; speedup vs baseline: 1.0249x; 1.0148x over previous
//
#include <hip/hip_runtime.h>

// Problem constants (B=2,S=1024 -> T=2048; H=1024, I=512, SI=2048, E=8, TOPK=2)
#define T_TOK 2048
#define H_DIM 1024
#define I_DIM 512
#define SI_DIM 2048
#define E_NUM 8
#define NSLOT 4096  // total expert slots: exactly 2 per token

typedef __attribute__((ext_vector_type(8))) short short8;   // 8 x bf16 (4 VGPRs)
typedef __attribute__((ext_vector_type(4))) float floatx4;  // MFMA C/D

// fp32 -> bf16 round-to-nearest-even
__device__ inline unsigned short f2bf(float f) {
  unsigned u = __builtin_bit_cast(unsigned, f);
  u = (u + 0x7FFFu + ((u >> 16) & 1u)) >> 16;
  return (unsigned short)u;
}
__device__ inline float bf2f(unsigned short u) {
  return __builtin_bit_cast(float, (unsigned)u << 16);
}

// async global->LDS, 16B per lane; LDS dest = wave-uniform base + lane*16
__device__ inline void gl_lds16(const void* g, void* l) {
  __builtin_amdgcn_global_load_lds(
      (const __attribute__((address_space(1))) unsigned int*)g,
      (__attribute__((address_space(3))) unsigned int*)l, 16, 0, 0);
}

// ---------------------------------------------------------------------------
// Fused cast + router. Blocks [0,512): router (latency-bound, dispatched
// first so it overlaps the BW-bound cast flood). Blocks [512,14848): cast of
// ONLY the tensors swiglu needs (x, gate_up, shared gate/up). The down-proj
// weights are cast inside swiglu_fused (they're not needed until down_fused).
// ---------------------------------------------------------------------------
__global__ __launch_bounds__(256) void cast_router(
    const float* __restrict__ x, const float* __restrict__ rw,
    const float* __restrict__ segw,
    const float* __restrict__ s1,   // gate_up_proj
    const float* __restrict__ s3,   // shared_gate_w
    const float* __restrict__ s4,   // shared_up_w
    unsigned short* __restrict__ d0, unsigned short* __restrict__ d1,
    unsigned short* __restrict__ d3, unsigned short* __restrict__ d4,
    int* __restrict__ top2, float2* __restrict__ w01, float* __restrict__ sg) {
  const int bid = blockIdx.x;
  if (bid < 512) {
    // ---- router: one wave per token, fp32 logits (matches ref numerics) ----
    int t = bid * 4 + (threadIdx.x >> 6);
    int lane = threadIdx.x & 63;
    const float* xt = x + (long)t * H_DIM;
    float xv[16];
#pragma unroll
    for (int j = 0; j < 16; ++j) xv[j] = xt[j * 64 + lane];
    float dots[9];
#pragma unroll
    for (int e = 0; e < 8; ++e) {
      const float* w = rw + e * H_DIM;
      float s = 0.f;
#pragma unroll
      for (int j = 0; j < 16; ++j) s += xv[j] * w[j * 64 + lane];
      dots[e] = s;
    }
    {
      float s = 0.f;
#pragma unroll
      for (int j = 0; j < 16; ++j) s += xv[j] * segw[j * 64 + lane];
      dots[8] = s;
    }
#pragma unroll
    for (int off = 32; off > 0; off >>= 1) {
#pragma unroll
      for (int e = 0; e < 9; ++e) dots[e] += __shfl_xor(dots[e], off, 64);
    }
    if (lane == 0) {
      int e0 = 0;
      for (int e = 1; e < 8; ++e)
        if (dots[e] > dots[e0]) e0 = e;
      int e1 = (e0 == 0) ? 1 : 0;
      for (int e = 0; e < 8; ++e)
        if (e != e0 && dots[e] > dots[e1]) e1 = e;
      float p1 = expf(dots[e1] - dots[e0]);
      top2[t] = e0 | (e1 << 8);
      w01[t] = make_float2(1.f / (1.f + p1), p1 / (1.f + p1));
      sg[t] = 1.f / (1.f + expf(-dots[8]));
    }
  } else {
    // ---- cast: 4 fp32 segments -> bf16, 4 elems/thread (3,670,016 groups) --
    long g = (long)(bid - 512) * 256 + threadIdx.x;
    const float* s;
    unsigned short* d;
    long off;
    if (g < 524288L)       { s = x;  d = d0; off = g; }            // x
    else if (g < 2621440L) { s = s1; d = d1; off = g - 524288L; }  // gate_up
    else if (g < 3145728L) { s = s3; d = d3; off = g - 2621440L; } // shared_gate
    else                   { s = s4; d = d4; off = g - 3145728L; } // shared_up
    float4 v = ((const float4*)s)[off];
    ushort4 o;
    o.x = f2bf(v.x); o.y = f2bf(v.y); o.z = f2bf(v.z); o.w = f2bf(v.w);
    ((ushort4*)d)[off] = o;
  }
}

// ---------------------------------------------------------------------------
// Router phase 2: one block per expert; block-wide scan -> compact slot list
// (global base = #assignments to experts < e) + tok_slot back-pointers.
// ---------------------------------------------------------------------------
__global__ __launch_bounds__(256) void build_lists(
    const int* __restrict__ top2, int* __restrict__ cnt, int* __restrict__ ebase,
    int* __restrict__ slot_token, int* __restrict__ tok_slot) {
  const int e = blockIdx.x;
  const int tid = threadIdx.x;
  const int lane = tid & 63, wid = tid >> 6;
  __shared__ int wsum[4], wbelow[4];
  const int base_t = tid * 8;  // 2048 / 256
  int mk[8], kk[8];
  int c = 0, below = 0;
#pragma unroll
  for (int j = 0; j < 8; ++j) {
    int p = top2[base_t + j];
    int e0 = p & 0xFF, e1 = (p >> 8) & 0xFF;
    below += (e0 < e) + (e1 < e);
    int m = 0, k = 0;
    if (e0 == e) { m = 1; k = 0; }
    else if (e1 == e) { m = 1; k = 1; }
    mk[j] = m; kk[j] = k;
    c += m;
  }
  int inc = c;
#pragma unroll
  for (int off = 1; off < 64; off <<= 1) {
    int n = __shfl_up(inc, off, 64);
    if (lane >= off) inc += n;
  }
  int bsum = below;
#pragma unroll
  for (int off = 32; off > 0; off >>= 1) bsum += __shfl_xor(bsum, off, 64);
  if (lane == 63) wsum[wid] = inc;
  if (lane == 0) wbelow[wid] = bsum;
  __syncthreads();
  int woff = 0;
#pragma unroll
  for (int i = 0; i < 4; ++i)
    if (i < wid) woff += wsum[i];
  int baseE = wbelow[0] + wbelow[1] + wbelow[2] + wbelow[3];
  int pos = baseE + woff + inc - c;
#pragma unroll
  for (int j = 0; j < 8; ++j) {
    if (mk[j]) {
      slot_token[pos] = base_t + j;
      tok_slot[2 * (base_t + j) + kk[j]] = pos;
      pos++;
    }
  }
  if (tid == 255) cnt[e] = woff + inc;
  if (tid == 0) ebase[e] = baseE;
}

// ---------------------------------------------------------------------------
// Fused SwiGLU GEMM body: act = silu(A@Bg^T)*(A@Bu^T), bf16, fp32 acc.
// BM=128, BN=128, BK=32, 256 threads = 4 waves (2m x 2n); wave 64x64 for
// both G and U: 12 ds_read_b128 -> 32 MFMA per wave-iter (round-7 shape,
// the measured plateau of this 2-barrier structure).
// Double-buffered LDS (1 barrier/iter) + XOR bank swizzle (0 conflicts).
// ---------------------------------------------------------------------------
template <bool GATHER>
__device__ __forceinline__ void swiglu_body(
    char* smem, int bx, int by, int e,
    const unsigned short* __restrict__ A, const unsigned short* __restrict__ Bg,
    const unsigned short* __restrict__ Bu, unsigned short* __restrict__ Out,
    const int* __restrict__ slot_token, const int* __restrict__ cnt,
    const int* __restrict__ ebase, int N, int K, long estrideB) {
  constexpr int BM = 128, BN = 128, BK = 32;
  constexpr int ATILE = BM * BK;
  constexpr int BTILE = BN * BK;
  const int tid = threadIdx.x;
  const int lane = tid & 63;
  const int wid = tid >> 6;  // 0..3
  const int wm = wid & 1;
  const int wn = wid >> 1;
  const int m0 = by * BM;
  const int n0 = bx * BN;
  int Meff = 0, baseE = 0;
  if (GATHER) {
    Meff = cnt[e];
    if (m0 >= Meff) return;
    baseE = ebase[e];
  }
  const unsigned short* BgE = Bg + (long)e * estrideB;
  const unsigned short* BuE = Bu + (long)e * estrideB;

  unsigned short* As = (unsigned short*)smem;  // [2][128*32]
  unsigned short* Bgs = As + 2 * ATILE;        // [2][128*32]
  unsigned short* Bus = Bgs + 2 * BTILE;       // [2][128*32]

  const int lrow = lane >> 2;  // 16 rows / 1KB chunk
  const int lcol = (((lane & 3) ^ ((lrow >> 1) & 3)) << 4);  // swizzled 16B col

  const char* aP[2];
  const char* bgP[2];
  const char* buP[2];
#pragma unroll
  for (int i = 0; i < 2; ++i) {
    int m = m0 + wid * 32 + i * 16 + lrow;
    long row;
    if (GATHER) {
      int mm = (m < Meff - 1) ? m : (Meff - 1);  // clamp tail to valid slot
      row = slot_token[baseE + mm];
    } else {
      row = m;
    }
    aP[i] = (const char*)A + row * (long)(K * 2) + lcol;
    int n = n0 + wid * 32 + i * 16 + lrow;
    bgP[i] = (const char*)BgE + (long)n * (K * 2) + lcol;
    buP[i] = (const char*)BuE + (long)n * (K * 2) + lcol;
  }

  floatx4 accG[4][4], accU[4][4];
  floatx4 zero = {0.f, 0.f, 0.f, 0.f};
#pragma unroll
  for (int i = 0; i < 4; ++i)
#pragma unroll
    for (int j = 0; j < 4; ++j) { accG[i][j] = zero; accU[i][j] = zero; }

  const int ar = lane & 15;
  const int aksw = (((lane >> 4) ^ ((ar >> 1) & 3)) << 3);  // swizzled k-chunk

  auto stage = [&](int p, int k0) {
#pragma unroll
    for (int i = 0; i < 2; ++i) {
      gl_lds16(aP[i] + (long)k0 * 2, &As[p * ATILE + (wid * 32 + i * 16) * BK]);
      gl_lds16(bgP[i] + (long)k0 * 2, &Bgs[p * BTILE + (wid * 32 + i * 16) * BK]);
      gl_lds16(buP[i] + (long)k0 * 2, &Bus[p * BTILE + (wid * 32 + i * 16) * BK]);
    }
  };

  stage(0, 0);
  const int NI = K / BK;
  for (int i = 0; i < NI; ++i) {
    __syncthreads();  // vmcnt drained before barrier -> buf[i&1] ready
    if (i + 1 < NI) stage((i + 1) & 1, (i + 1) * BK);
    const unsigned short* Ab = &As[(i & 1) * ATILE];
    const unsigned short* Gb = &Bgs[(i & 1) * BTILE];
    const unsigned short* Ub = &Bus[(i & 1) * BTILE];
    short8 af[4], bgf[4], buf2[4];
#pragma unroll
    for (int tm = 0; tm < 4; ++tm)
      af[tm] = *(const short8*)&Ab[(wm * 64 + tm * 16 + ar) * BK + aksw];
#pragma unroll
    for (int tn = 0; tn < 4; ++tn) {
      bgf[tn] = *(const short8*)&Gb[(wn * 64 + tn * 16 + ar) * BK + aksw];
      buf2[tn] = *(const short8*)&Ub[(wn * 64 + tn * 16 + ar) * BK + aksw];
    }
#pragma unroll
    for (int tm = 0; tm < 4; ++tm)
#pragma unroll
      for (int tn = 0; tn < 4; ++tn) {
        accG[tm][tn] = __builtin_amdgcn_mfma_f32_16x16x32_bf16(af[tm], bgf[tn], accG[tm][tn], 0, 0, 0);
        accU[tm][tn] = __builtin_amdgcn_mfma_f32_16x16x32_bf16(af[tm], buf2[tn], accU[tm][tn], 0, 0, 0);
      }
  }

#pragma unroll
  for (int tm = 0; tm < 4; ++tm)
#pragma unroll
    for (int tn = 0; tn < 4; ++tn)
#pragma unroll
      for (int r = 0; r < 4; ++r) {
        int row = m0 + wm * 64 + tm * 16 + (lane >> 4) * 4 + r;
        int col = n0 + wn * 64 + tn * 16 + (lane & 15);
        if (!GATHER || row < Meff) {
          float g = accG[tm][tn][r];
          float u = accU[tm][tn][r];
          float act = g / (1.f + expf(-g)) * u;
          Out[(long)(baseE + row) * N + col] = f2bf(act);
        }
      }
}

// Fused launch (256 threads):
//   [0,256)    shared SwiGLU (BM128xBN128: 16bx x 16by)
//   [256,768)  expert SwiGLU (BM128xBN128: 4bx x 16by per expert, ~128 active)
//   [768,6912) cast of down-proj weights (dwn 1,048,576 + sdw 524,288 float4
//              groups = 6144 blocks) — overlaps the GEMM tail; consumed only
//              by the NEXT kernel (down_fused), so no ordering hazard.
__global__ __launch_bounds__(256, 2) void swiglu_fused(
    const unsigned short* __restrict__ xb, const unsigned short* __restrict__ sgate,
    const unsigned short* __restrict__ sup, unsigned short* __restrict__ act_s,
    const unsigned short* __restrict__ gup, unsigned short* __restrict__ act_e,
    const int* __restrict__ slot_token, const int* __restrict__ cnt,
    const int* __restrict__ ebase,
    const float* __restrict__ dwn_f, const float* __restrict__ sdw_f,
    unsigned short* __restrict__ down_b, unsigned short* __restrict__ sdown_b) {
  __shared__ __align__(16) char smem[49152];
  int bid = blockIdx.x;
  if (bid < 256) {
    swiglu_body<false>(smem, bid & 15, bid >> 4, 0, xb, sgate, sup, act_s,
                       nullptr, nullptr, nullptr, SI_DIM, H_DIM, 0);
  } else if (bid < 768) {
    int b2 = bid - 256;
    int e = b2 >> 6;
    int rem = b2 & 63;  // bx in [0,4), by in [0,16)
    swiglu_body<true>(smem, rem & 3, rem >> 2, e, xb, gup,
                      gup + (long)I_DIM * H_DIM, act_e, slot_token, cnt,
                      ebase, I_DIM, H_DIM, (long)2 * I_DIM * H_DIM);
  } else {
    long g = (long)(bid - 768) * 256 + threadIdx.x;
    const float* s;
    unsigned short* d;
    long off;
    if (g < 1048576L) { s = dwn_f; d = down_b; off = g; }
    else              { s = sdw_f; d = sdown_b; off = g - 1048576L; }
    float4 v = ((const float4*)s)[off];
    ushort4 o;
    o.x = f2bf(v.x); o.y = f2bf(v.y); o.z = f2bf(v.z); o.w = f2bf(v.w);
    ((ushort4*)d)[off] = o;
  }
}

// ---------------------------------------------------------------------------
// Down-proj GEMM body: C = A@B^T. BM=128, BN=128, BK=32, 256 threads
// (4 waves 2m x 2n, wave 64x64): 8 ds_read_b128 -> 16 MFMA per wave-iter.
// MODE 0: shared split-K part 0 -> OutF[row][col] = v (raw fp32)
// MODE 2: shared split-K part 1 -> OutB[row][col] = bf16(v)
// MODE 1: expert -> OutB[(baseE+row)][col] = bf16(v)
// ---------------------------------------------------------------------------
template <int MODE>
__device__ __forceinline__ void down_body(
    char* smem, int bx, int by, int e,
    const unsigned short* __restrict__ A, const unsigned short* __restrict__ B,
    float* __restrict__ OutF, unsigned short* __restrict__ OutB,
    const int* __restrict__ ebase, const int* __restrict__ cnt,
    int N, int Kstride, int kbeg, int kcnt, long estrideB) {
  constexpr int BM = 128, BN = 128, BK = 32;
  constexpr int ATILE = BM * BK;
  constexpr int BTILE = BN * BK;
  const int tid = threadIdx.x;
  const int lane = tid & 63;
  const int wid = tid >> 6;
  const int wm = wid & 1;
  const int wn = wid >> 1;
  const int m0 = by * BM;
  const int n0 = bx * BN;
  int Meff = 0, baseE = 0;
  if (MODE == 1) {
    Meff = cnt[e];
    if (m0 >= Meff) return;
    baseE = ebase[e];
  }
  const unsigned short* BE = B + (long)e * estrideB;

  unsigned short* As = (unsigned short*)smem;  // [2][128*32]
  unsigned short* Bs = As + 2 * ATILE;         // [2][128*32]

  const int lrow = lane >> 2;
  const int lcol = (((lane & 3) ^ ((lrow >> 1) & 3)) << 4);

  const char* aP[2];
  const char* bP[2];
#pragma unroll
  for (int i = 0; i < 2; ++i) {
    int m = m0 + wid * 32 + i * 16 + lrow;
    long arow;
    if (MODE == 1) {
      int mm = (m < Meff - 1) ? m : (Meff - 1);
      arow = baseE + mm;
    } else {
      arow = m;
    }
    aP[i] = (const char*)A + arow * (long)(Kstride * 2) + (long)kbeg * 2 + lcol;
    int n = n0 + wid * 32 + i * 16 + lrow;
    bP[i] = (const char*)BE + (long)n * (Kstride * 2) + (long)kbeg * 2 + lcol;
  }

  floatx4 acc[4][4];
  floatx4 zero = {0.f, 0.f, 0.f, 0.f};
#pragma unroll
  for (int i = 0; i < 4; ++i)
#pragma unroll
    for (int j = 0; j < 4; ++j) acc[i][j] = zero;

  const int ar = lane & 15;
  const int aksw = (((lane >> 4) ^ ((ar >> 1) & 3)) << 3);

  auto stage = [&](int p, int k0) {
#pragma unroll
    for (int i = 0; i < 2; ++i) {
      gl_lds16(aP[i] + (long)k0 * 2, &As[p * ATILE + (wid * 32 + i * 16) * BK]);
      gl_lds16(bP[i] + (long)k0 * 2, &Bs[p * BTILE + (wid * 32 + i * 16) * BK]);
    }
  };

  stage(0, 0);
  const int NI = kcnt / BK;
  for (int i = 0; i < NI; ++i) {
    __syncthreads();
    if (i + 1 < NI) stage((i + 1) & 1, (i + 1) * BK);
    const unsigned short* Ab = &As[(i & 1) * ATILE];
    const unsigned short* Bb = &Bs[(i & 1) * BTILE];
    short8 af[4], bf[4];
#pragma unroll
    for (int tm = 0; tm < 4; ++tm)
      af[tm] = *(const short8*)&Ab[(wm * 64 + tm * 16 + ar) * BK + aksw];
#pragma unroll
    for (int tn = 0; tn < 4; ++tn)
      bf[tn] = *(const short8*)&Bb[(wn * 64 + tn * 16 + ar) * BK + aksw];
#pragma unroll
    for (int tm = 0; tm < 4; ++tm)
#pragma unroll
      for (int tn = 0; tn < 4; ++tn)
        acc[tm][tn] = __builtin_amdgcn_mfma_f32_16x16x32_bf16(af[tm], bf[tn], acc[tm][tn], 0, 0, 0);
  }

#pragma unroll
  for (int tm = 0; tm < 4; ++tm)
#pragma unroll
    for (int r = 0; r < 4; ++r) {
      int row = m0 + wm * 64 + tm * 16 + (lane >> 4) * 4 + r;
#pragma unroll
      for (int tn = 0; tn < 4; ++tn) {
        int col = n0 + wn * 64 + tn * 16 + (lane & 15);
        float v = acc[tm][tn][r];
        if (MODE == 0) {
          OutF[(long)row * N + col] = v;
        } else if (MODE == 2) {
          OutB[(long)row * N + col] = f2bf(v);
        } else if (row < Meff) {
          OutB[(long)(baseE + row) * N + col] = f2bf(v);
        }
      }
    }
}

// Fused launch (256 threads): [0,256) shared down split-K
// (ks = bid>>7; 8bx x 16by): ks0 -> out raw fp32, ks1 -> spart bf16;
// [256,1280) expert down (8bx x 16by per expert; ~32 active -> ~256 active).
__global__ __launch_bounds__(256, 2) void down_fused(
    const unsigned short* __restrict__ act_s, const unsigned short* __restrict__ sdown,
    float* __restrict__ out, unsigned short* __restrict__ spart,
    const unsigned short* __restrict__ act_e, const unsigned short* __restrict__ downw,
    unsigned short* __restrict__ eout, const int* __restrict__ ebase,
    const int* __restrict__ cnt) {
  __shared__ __align__(16) char smem[32768];
  int bid = blockIdx.x;
  if (bid < 256) {
    int ks = bid >> 7;
    int rem = bid & 127;  // bx in [0,8), by in [0,16)
    if (ks == 0)
      down_body<0>(smem, rem & 7, rem >> 3, 0, act_s, sdown, out, nullptr,
                   nullptr, nullptr, H_DIM, SI_DIM, 0, 1024, 0);
    else
      down_body<2>(smem, rem & 7, rem >> 3, 0, act_s, sdown, nullptr, spart,
                   nullptr, nullptr, H_DIM, SI_DIM, 1024, 1024, 0);
  } else {
    int b2 = bid - 256;
    int e = b2 >> 7;
    int rem = b2 & 127;  // bx in [0,8), by in [0,16)
    down_body<1>(smem, rem & 7, rem >> 3, e, act_e, downw, nullptr, eout,
                 ebase, cnt, H_DIM, I_DIM, 0, I_DIM, (long)H_DIM * I_DIM);
  }
}

// ---------------------------------------------------------------------------
// Combine: out[t][h] = sg[t]*(p0 + p1) + w0*eout[s0][h] + w1*eout[s1][h].
// p0 = raw fp32 in out, p1 = bf16 in spart. One block per token.
// ---------------------------------------------------------------------------
__global__ __launch_bounds__(256) void combine_kernel(
    float* __restrict__ out, const unsigned short* __restrict__ spart,
    const unsigned short* __restrict__ eout, const float* __restrict__ sg,
    const float2* __restrict__ w01, const int* __restrict__ tok_slot) {
  int t = blockIdx.x;
  int c = threadIdx.x;  // 256 threads x 4 elems = 1024
  float sgr = sg[t];
  float2 wr = w01[t];
  int s0 = tok_slot[2 * t];
  int s1 = tok_slot[2 * t + 1];
  ushort4 p1 = ((const ushort4*)(spart + (long)t * H_DIM))[c];
  ushort4 e0 = ((const ushort4*)(eout + (long)s0 * H_DIM))[c];
  ushort4 e1 = ((const ushort4*)(eout + (long)s1 * H_DIM))[c];
  float4* op = &((float4*)(out + (long)t * H_DIM))[c];
  float4 o = *op;
  o.x = sgr * (o.x + bf2f(p1.x)) + wr.x * bf2f(e0.x) + wr.y * bf2f(e1.x);
  o.y = sgr * (o.y + bf2f(p1.y)) + wr.x * bf2f(e0.y) + wr.y * bf2f(e1.y);
  o.z = sgr * (o.z + bf2f(p1.z)) + wr.x * bf2f(e0.z) + wr.y * bf2f(e1.z);
  o.w = sgr * (o.w + bf2f(p1.w)) + wr.x * bf2f(e0.w) + wr.y * bf2f(e1.w);
  *op = o;
}

// ---------------------------------------------------------------------------
// Workspace map (bytes), total ~63.0 MB (ws proven >= 67.25 MB in round 1):
//   0         xb       bf16[2048][1024]     (reused as spart by down split-K)
//   4194304   gup_b    bf16[8][1024][1024]
//  20971520   down_b   bf16[8][1024][512]   (cast inside swiglu_fused)
//  29360128   sgate_b  bf16[2048][1024]
//  33554432   sup_b    bf16[2048][1024]
//  37748736   sdown_b  bf16[1024][2048]     (cast inside swiglu_fused)
//  41943040   act_s    bf16[2048][2048]
//  50331648   act_e    bf16[4096][512]
//  54525952   eout     bf16[4096][1024]
//  62914560   sg / top2 / w01 / cnt / ebase / slot_token / tok_slot
// ---------------------------------------------------------------------------
extern "C" void kernel_launch(void* const* d_in, const int* in_sizes, int n_in,
                              void* d_out, int out_size, void* d_ws, size_t ws_size,
                              hipStream_t stream) {
  const float* x = (const float*)d_in[0];
  const float* rw = (const float*)d_in[1];
  const float* gup = (const float*)d_in[2];
  const float* dwn = (const float*)d_in[3];
  const float* sgw = (const float*)d_in[4];
  const float* suw = (const float*)d_in[5];
  const float* sdw = (const float*)d_in[6];
  const float* segw = (const float*)d_in[7];
  float* out = (float*)d_out;

  char* w = (char*)d_ws;
  unsigned short* xb = (unsigned short*)(w + 0);
  unsigned short* gup_b = (unsigned short*)(w + 4194304L);
  unsigned short* down_b = (unsigned short*)(w + 20971520L);
  unsigned short* sgate_b = (unsigned short*)(w + 29360128L);
  unsigned short* sup_b = (unsigned short*)(w + 33554432L);
  unsigned short* sdown_b = (unsigned short*)(w + 37748736L);
  unsigned short* act_s = (unsigned short*)(w + 41943040L);
  unsigned short* act_e = (unsigned short*)(w + 50331648L);
  unsigned short* eout = (unsigned short*)(w + 54525952L);
  float* sg = (float*)(w + 62914560L);
  int* top2 = (int*)(w + 62922752L);
  float2* w01 = (float2*)(w + 62930944L);
  int* cnt = (int*)(w + 62947328L);
  int* ebase = (int*)(w + 62947584L);
  int* slot_token = (int*)(w + 62947840L);
  int* tok_slot = (int*)(w + 62964224L);
  unsigned short* spart = xb;  // xb dead after swiglu_fused; reuse for split-K partial

  // router (512 blocks, first) + cast of swiglu-needed tensors (14336 blocks)
  cast_router<<<14848, 256, 0, stream>>>(x, rw, segw, gup, sgw, suw,
                                         xb, gup_b, sgate_b, sup_b,
                                         top2, w01, sg);
  build_lists<<<E_NUM, 256, 0, stream>>>(top2, cnt, ebase, slot_token, tok_slot);
  // fused shared+expert SwiGLU + down-weight cast tail (6144 cast blocks)
  swiglu_fused<<<6912, 256, 0, stream>>>(xb, sgate_b, sup_b, act_s, gup_b,
                                         act_e, slot_token, cnt, ebase,
                                         dwn, sdw, down_b, sdown_b);
  // fused shared (split-K x2) + expert down-proj
  down_fused<<<1280, 256, 0, stream>>>(act_s, sdown_b, out, spart, act_e,
                                       down_b, eout, ebase, cnt);
  // out = sg*(p0+p1) + w0*eout[s0] + w1*eout[s1]
  combine_kernel<<<T_TOK, 256, 0, stream>>>(out, spart, eout, sg, w01, tok_slot);
}

// Round 11
// 199.397 us; speedup vs baseline: 1.0603x; 1.0345x over previous
//
#include <hip/hip_runtime.h>

// Problem constants (B=2,S=1024 -> T=2048; H=1024, I=512, SI=2048, E=8, TOPK=2)
#define T_TOK 2048
#define H_DIM 1024
#define I_DIM 512
#define SI_DIM 2048
#define E_NUM 8
#define NSLOT 4096  // total expert slots: exactly 2 per token

typedef __attribute__((ext_vector_type(8))) short short8;   // 8 x bf16 (4 VGPRs)
typedef __attribute__((ext_vector_type(4))) float floatx4;  // MFMA C/D

// fp32 -> bf16 round-to-nearest-even
__device__ inline unsigned short f2bf(float f) {
  unsigned u = __builtin_bit_cast(unsigned, f);
  u = (u + 0x7FFFu + ((u >> 16) & 1u)) >> 16;
  return (unsigned short)u;
}
__device__ inline float bf2f(unsigned short u) {
  return __builtin_bit_cast(float, (unsigned)u << 16);
}

// async global->LDS, 16B per lane; LDS dest = wave-uniform base + lane*16
__device__ inline void gl_lds16(const void* g, void* l) {
  __builtin_amdgcn_global_load_lds(
      (const __attribute__((address_space(1))) unsigned int*)g,
      (__attribute__((address_space(3))) unsigned int*)l, 16, 0, 0);
}

// ---------------------------------------------------------------------------
// Fused cast + router. Blocks [0,512): router (latency-bound, dispatched
// first so it overlaps the BW-bound cast flood). Blocks [512,20992): cast of
// ALL six fp32 tensors -> bf16. (Round-10 experiment moved the down-weight
// cast into swiglu_fused: measured neutral — the GEMM is fully occupied, so
// appended cast blocks serialize. Reverted.)
// ---------------------------------------------------------------------------
__global__ __launch_bounds__(256) void cast_router(
    const float* __restrict__ x, const float* __restrict__ rw,
    const float* __restrict__ segw,
    const float* __restrict__ s1, const float* __restrict__ s2,
    const float* __restrict__ s3, const float* __restrict__ s4,
    const float* __restrict__ s5,
    unsigned short* __restrict__ d0, unsigned short* __restrict__ d1,
    unsigned short* __restrict__ d2, unsigned short* __restrict__ d3,
    unsigned short* __restrict__ d4, unsigned short* __restrict__ d5,
    int* __restrict__ top2, float2* __restrict__ w01, float* __restrict__ sg) {
  const int bid = blockIdx.x;
  if (bid < 512) {
    // ---- router: one wave per token, fp32 logits (matches ref numerics) ----
    int t = bid * 4 + (threadIdx.x >> 6);
    int lane = threadIdx.x & 63;
    const float* xt = x + (long)t * H_DIM;
    float xv[16];
#pragma unroll
    for (int j = 0; j < 16; ++j) xv[j] = xt[j * 64 + lane];
    float dots[9];
#pragma unroll
    for (int e = 0; e < 8; ++e) {
      const float* w = rw + e * H_DIM;
      float s = 0.f;
#pragma unroll
      for (int j = 0; j < 16; ++j) s += xv[j] * w[j * 64 + lane];
      dots[e] = s;
    }
    {
      float s = 0.f;
#pragma unroll
      for (int j = 0; j < 16; ++j) s += xv[j] * segw[j * 64 + lane];
      dots[8] = s;
    }
#pragma unroll
    for (int off = 32; off > 0; off >>= 1) {
#pragma unroll
      for (int e = 0; e < 9; ++e) dots[e] += __shfl_xor(dots[e], off, 64);
    }
    if (lane == 0) {
      int e0 = 0;
      for (int e = 1; e < 8; ++e)
        if (dots[e] > dots[e0]) e0 = e;
      int e1 = (e0 == 0) ? 1 : 0;
      for (int e = 0; e < 8; ++e)
        if (e != e0 && dots[e] > dots[e1]) e1 = e;
      float p1 = expf(dots[e1] - dots[e0]);
      top2[t] = e0 | (e1 << 8);
      w01[t] = make_float2(1.f / (1.f + p1), p1 / (1.f + p1));
      sg[t] = 1.f / (1.f + expf(-dots[8]));
    }
  } else {
    // ---- cast: 6 fp32 segments -> bf16, 4 elems/thread ----
    long g = (long)(bid - 512) * 256 + threadIdx.x;
    const float* s;
    unsigned short* d;
    long off;
    if (g < 524288L)       { s = x;  d = d0; off = g; }            // x
    else if (g < 2621440L) { s = s1; d = d1; off = g - 524288L; }  // gate_up
    else if (g < 3670016L) { s = s2; d = d2; off = g - 2621440L; } // down
    else if (g < 4194304L) { s = s3; d = d3; off = g - 3670016L; } // shared_gate
    else if (g < 4718592L) { s = s4; d = d4; off = g - 4194304L; } // shared_up
    else                   { s = s5; d = d5; off = g - 4718592L; } // shared_down
    float4 v = ((const float4*)s)[off];
    ushort4 o;
    o.x = f2bf(v.x); o.y = f2bf(v.y); o.z = f2bf(v.z); o.w = f2bf(v.w);
    ((ushort4*)d)[off] = o;
  }
}

// ---------------------------------------------------------------------------
// Router phase 2: one block per expert; block-wide scan -> compact slot list
// (global base = #assignments to experts < e) + tok_slot back-pointers.
// ---------------------------------------------------------------------------
__global__ __launch_bounds__(256) void build_lists(
    const int* __restrict__ top2, int* __restrict__ cnt, int* __restrict__ ebase,
    int* __restrict__ slot_token, int* __restrict__ tok_slot) {
  const int e = blockIdx.x;
  const int tid = threadIdx.x;
  const int lane = tid & 63, wid = tid >> 6;
  __shared__ int wsum[4], wbelow[4];
  const int base_t = tid * 8;  // 2048 / 256
  int mk[8], kk[8];
  int c = 0, below = 0;
#pragma unroll
  for (int j = 0; j < 8; ++j) {
    int p = top2[base_t + j];
    int e0 = p & 0xFF, e1 = (p >> 8) & 0xFF;
    below += (e0 < e) + (e1 < e);
    int m = 0, k = 0;
    if (e0 == e) { m = 1; k = 0; }
    else if (e1 == e) { m = 1; k = 1; }
    mk[j] = m; kk[j] = k;
    c += m;
  }
  int inc = c;
#pragma unroll
  for (int off = 1; off < 64; off <<= 1) {
    int n = __shfl_up(inc, off, 64);
    if (lane >= off) inc += n;
  }
  int bsum = below;
#pragma unroll
  for (int off = 32; off > 0; off >>= 1) bsum += __shfl_xor(bsum, off, 64);
  if (lane == 63) wsum[wid] = inc;
  if (lane == 0) wbelow[wid] = bsum;
  __syncthreads();
  int woff = 0;
#pragma unroll
  for (int i = 0; i < 4; ++i)
    if (i < wid) woff += wsum[i];
  int baseE = wbelow[0] + wbelow[1] + wbelow[2] + wbelow[3];
  int pos = baseE + woff + inc - c;
#pragma unroll
  for (int j = 0; j < 8; ++j) {
    if (mk[j]) {
      slot_token[pos] = base_t + j;
      tok_slot[2 * (base_t + j) + kk[j]] = pos;
      pos++;
    }
  }
  if (tid == 255) cnt[e] = woff + inc;
  if (tid == 0) ebase[e] = baseE;
}

// ---------------------------------------------------------------------------
// Fused SwiGLU GEMM body: act = silu(A@Bg^T)*(A@Bu^T), bf16, fp32 acc.
// BM=128, BN=128, BK=32, 256 threads = 4 waves (2m x 2n); wave 64x64 for
// both G and U: 12 ds_read_b128 -> 32 MFMA per wave-iter (the measured
// plateau shape of this 2-barrier structure, ~43 us).
// Double-buffered LDS (1 barrier/iter) + XOR bank swizzle (0 conflicts).
// ---------------------------------------------------------------------------
template <bool GATHER>
__device__ __forceinline__ void swiglu_body(
    char* smem, int bx, int by, int e,
    const unsigned short* __restrict__ A, const unsigned short* __restrict__ Bg,
    const unsigned short* __restrict__ Bu, unsigned short* __restrict__ Out,
    const int* __restrict__ slot_token, const int* __restrict__ cnt,
    const int* __restrict__ ebase, int N, int K, long estrideB) {
  constexpr int BM = 128, BN = 128, BK = 32;
  constexpr int ATILE = BM * BK;
  constexpr int BTILE = BN * BK;
  const int tid = threadIdx.x;
  const int lane = tid & 63;
  const int wid = tid >> 6;  // 0..3
  const int wm = wid & 1;
  const int wn = wid >> 1;
  const int m0 = by * BM;
  const int n0 = bx * BN;
  int Meff = 0, baseE = 0;
  if (GATHER) {
    Meff = cnt[e];
    if (m0 >= Meff) return;
    baseE = ebase[e];
  }
  const unsigned short* BgE = Bg + (long)e * estrideB;
  const unsigned short* BuE = Bu + (long)e * estrideB;

  unsigned short* As = (unsigned short*)smem;  // [2][128*32]
  unsigned short* Bgs = As + 2 * ATILE;        // [2][128*32]
  unsigned short* Bus = Bgs + 2 * BTILE;       // [2][128*32]

  const int lrow = lane >> 2;  // 16 rows / 1KB chunk
  const int lcol = (((lane & 3) ^ ((lrow >> 1) & 3)) << 4);  // swizzled 16B col

  const char* aP[2];
  const char* bgP[2];
  const char* buP[2];
#pragma unroll
  for (int i = 0; i < 2; ++i) {
    int m = m0 + wid * 32 + i * 16 + lrow;
    long row;
    if (GATHER) {
      int mm = (m < Meff - 1) ? m : (Meff - 1);  // clamp tail to valid slot
      row = slot_token[baseE + mm];
    } else {
      row = m;
    }
    aP[i] = (const char*)A + row * (long)(K * 2) + lcol;
    int n = n0 + wid * 32 + i * 16 + lrow;
    bgP[i] = (const char*)BgE + (long)n * (K * 2) + lcol;
    buP[i] = (const char*)BuE + (long)n * (K * 2) + lcol;
  }

  floatx4 accG[4][4], accU[4][4];
  floatx4 zero = {0.f, 0.f, 0.f, 0.f};
#pragma unroll
  for (int i = 0; i < 4; ++i)
#pragma unroll
    for (int j = 0; j < 4; ++j) { accG[i][j] = zero; accU[i][j] = zero; }

  const int ar = lane & 15;
  const int aksw = (((lane >> 4) ^ ((ar >> 1) & 3)) << 3);  // swizzled k-chunk

  auto stage = [&](int p, int k0) {
#pragma unroll
    for (int i = 0; i < 2; ++i) {
      gl_lds16(aP[i] + (long)k0 * 2, &As[p * ATILE + (wid * 32 + i * 16) * BK]);
      gl_lds16(bgP[i] + (long)k0 * 2, &Bgs[p * BTILE + (wid * 32 + i * 16) * BK]);
      gl_lds16(buP[i] + (long)k0 * 2, &Bus[p * BTILE + (wid * 32 + i * 16) * BK]);
    }
  };

  stage(0, 0);
  const int NI = K / BK;
  for (int i = 0; i < NI; ++i) {
    __syncthreads();  // vmcnt drained before barrier -> buf[i&1] ready
    if (i + 1 < NI) stage((i + 1) & 1, (i + 1) * BK);
    const unsigned short* Ab = &As[(i & 1) * ATILE];
    const unsigned short* Gb = &Bgs[(i & 1) * BTILE];
    const unsigned short* Ub = &Bus[(i & 1) * BTILE];
    short8 af[4], bgf[4], buf2[4];
#pragma unroll
    for (int tm = 0; tm < 4; ++tm)
      af[tm] = *(const short8*)&Ab[(wm * 64 + tm * 16 + ar) * BK + aksw];
#pragma unroll
    for (int tn = 0; tn < 4; ++tn) {
      bgf[tn] = *(const short8*)&Gb[(wn * 64 + tn * 16 + ar) * BK + aksw];
      buf2[tn] = *(const short8*)&Ub[(wn * 64 + tn * 16 + ar) * BK + aksw];
    }
#pragma unroll
    for (int tm = 0; tm < 4; ++tm)
#pragma unroll
      for (int tn = 0; tn < 4; ++tn) {
        accG[tm][tn] = __builtin_amdgcn_mfma_f32_16x16x32_bf16(af[tm], bgf[tn], accG[tm][tn], 0, 0, 0);
        accU[tm][tn] = __builtin_amdgcn_mfma_f32_16x16x32_bf16(af[tm], buf2[tn], accU[tm][tn], 0, 0, 0);
      }
  }

#pragma unroll
  for (int tm = 0; tm < 4; ++tm)
#pragma unroll
    for (int tn = 0; tn < 4; ++tn)
#pragma unroll
      for (int r = 0; r < 4; ++r) {
        int row = m0 + wm * 64 + tm * 16 + (lane >> 4) * 4 + r;
        int col = n0 + wn * 64 + tn * 16 + (lane & 15);
        if (!GATHER || row < Meff) {
          float g = accG[tm][tn][r];
          float u = accU[tm][tn][r];
          float act = g / (1.f + expf(-g)) * u;
          Out[(long)(baseE + row) * N + col] = f2bf(act);
        }
      }
}

// Fused launch (256 threads):
//   [0,256)   shared SwiGLU (BM128xBN128: 16bx x 16by)
//   [256,768) expert SwiGLU (BM128xBN128: 4bx x 16by per expert, ~128 active)
// Active ~384 blocks at 2/CU budget -> single residency generation.
__global__ __launch_bounds__(256, 2) void swiglu_fused(
    const unsigned short* __restrict__ xb, const unsigned short* __restrict__ sgate,
    const unsigned short* __restrict__ sup, unsigned short* __restrict__ act_s,
    const unsigned short* __restrict__ gup, unsigned short* __restrict__ act_e,
    const int* __restrict__ slot_token, const int* __restrict__ cnt,
    const int* __restrict__ ebase) {
  __shared__ __align__(16) char smem[49152];
  int bid = blockIdx.x;
  if (bid < 256) {
    swiglu_body<false>(smem, bid & 15, bid >> 4, 0, xb, sgate, sup, act_s,
                       nullptr, nullptr, nullptr, SI_DIM, H_DIM, 0);
  } else {
    int b2 = bid - 256;
    int e = b2 >> 6;
    int rem = b2 & 63;  // bx in [0,4), by in [0,16)
    swiglu_body<true>(smem, rem & 3, rem >> 2, e, xb, gup,
                      gup + (long)I_DIM * H_DIM, act_e, slot_token, cnt,
                      ebase, I_DIM, H_DIM, (long)2 * I_DIM * H_DIM);
  }
}

// ---------------------------------------------------------------------------
// Down-proj GEMM body: C = A@B^T. BM=128, BN=256, BK=32, 256 threads
// (4 waves 2m x 2n, wave 64x128): 12 ds_read_b128 -> 32 MFMA per wave-iter
// (0.375 reads/MFMA — was 0.5 at BN=128). LDS 48KB dbuf, XOR swizzle.
// MODE 0: shared split-K part 0 -> OutF[row][col] = v (raw fp32)
// MODE 2: shared split-K part 1 -> OutB[row][col] = bf16(v)
// MODE 1: expert -> OutB[(baseE+row)][col] = bf16(v)
// ---------------------------------------------------------------------------
template <int MODE>
__device__ __forceinline__ void down_body(
    char* smem, int bx, int by, int e,
    const unsigned short* __restrict__ A, const unsigned short* __restrict__ B,
    float* __restrict__ OutF, unsigned short* __restrict__ OutB,
    const int* __restrict__ ebase, const int* __restrict__ cnt,
    int N, int Kstride, int kbeg, int kcnt, long estrideB) {
  constexpr int BM = 128, BN = 256, BK = 32;
  constexpr int ATILE = BM * BK;   // 4096 ushorts
  constexpr int BTILE = BN * BK;   // 8192 ushorts
  const int tid = threadIdx.x;
  const int lane = tid & 63;
  const int wid = tid >> 6;
  const int wm = wid & 1;
  const int wn = wid >> 1;
  const int m0 = by * BM;
  const int n0 = bx * BN;
  int Meff = 0, baseE = 0;
  if (MODE == 1) {
    Meff = cnt[e];
    if (m0 >= Meff) return;
    baseE = ebase[e];
  }
  const unsigned short* BE = B + (long)e * estrideB;

  unsigned short* As = (unsigned short*)smem;  // [2][128*32]
  unsigned short* Bs = As + 2 * ATILE;         // [2][256*32]

  const int lrow = lane >> 2;
  const int lcol = (((lane & 3) ^ ((lrow >> 1) & 3)) << 4);

  const char* aP[2];
  const char* bP[4];
#pragma unroll
  for (int i = 0; i < 2; ++i) {
    int m = m0 + wid * 32 + i * 16 + lrow;
    long arow;
    if (MODE == 1) {
      int mm = (m < Meff - 1) ? m : (Meff - 1);
      arow = baseE + mm;
    } else {
      arow = m;
    }
    aP[i] = (const char*)A + arow * (long)(Kstride * 2) + (long)kbeg * 2 + lcol;
  }
#pragma unroll
  for (int i = 0; i < 4; ++i) {
    int n = n0 + wid * 64 + i * 16 + lrow;
    bP[i] = (const char*)BE + (long)n * (Kstride * 2) + (long)kbeg * 2 + lcol;
  }

  floatx4 acc[4][8];
  floatx4 zero = {0.f, 0.f, 0.f, 0.f};
#pragma unroll
  for (int i = 0; i < 4; ++i)
#pragma unroll
    for (int j = 0; j < 8; ++j) acc[i][j] = zero;

  const int ar = lane & 15;
  const int aksw = (((lane >> 4) ^ ((ar >> 1) & 3)) << 3);

  auto stage = [&](int p, int k0) {
#pragma unroll
    for (int i = 0; i < 2; ++i)
      gl_lds16(aP[i] + (long)k0 * 2, &As[p * ATILE + (wid * 32 + i * 16) * BK]);
#pragma unroll
    for (int i = 0; i < 4; ++i)
      gl_lds16(bP[i] + (long)k0 * 2, &Bs[p * BTILE + (wid * 64 + i * 16) * BK]);
  };

  stage(0, 0);
  const int NI = kcnt / BK;
  for (int i = 0; i < NI; ++i) {
    __syncthreads();
    if (i + 1 < NI) stage((i + 1) & 1, (i + 1) * BK);
    const unsigned short* Ab = &As[(i & 1) * ATILE];
    const unsigned short* Bb = &Bs[(i & 1) * BTILE];
    short8 af[4], bf[8];
#pragma unroll
    for (int tm = 0; tm < 4; ++tm)
      af[tm] = *(const short8*)&Ab[(wm * 64 + tm * 16 + ar) * BK + aksw];
#pragma unroll
    for (int tn = 0; tn < 8; ++tn)
      bf[tn] = *(const short8*)&Bb[(wn * 128 + tn * 16 + ar) * BK + aksw];
#pragma unroll
    for (int tm = 0; tm < 4; ++tm)
#pragma unroll
      for (int tn = 0; tn < 8; ++tn)
        acc[tm][tn] = __builtin_amdgcn_mfma_f32_16x16x32_bf16(af[tm], bf[tn], acc[tm][tn], 0, 0, 0);
  }

#pragma unroll
  for (int tm = 0; tm < 4; ++tm)
#pragma unroll
    for (int r = 0; r < 4; ++r) {
      int row = m0 + wm * 64 + tm * 16 + (lane >> 4) * 4 + r;
#pragma unroll
      for (int tn = 0; tn < 8; ++tn) {
        int col = n0 + wn * 128 + tn * 16 + (lane & 15);
        float v = acc[tm][tn][r];
        if (MODE == 0) {
          OutF[(long)row * N + col] = v;
        } else if (MODE == 2) {
          OutB[(long)row * N + col] = f2bf(v);
        } else if (row < Meff) {
          OutB[(long)(baseE + row) * N + col] = f2bf(v);
        }
      }
    }
}

// Fused launch (256 threads):
//   [0,128)   shared down split-K (ks = bid>>6; 4bx x 16by):
//             ks0 -> out raw fp32, ks1 -> spart bf16 (NI=32 each)
//   [128,640) expert down (4bx x 16by per expert; ~32 active -> ~256 active,
//             NI=16)
// Active ~384 blocks at 2/CU budget -> single residency generation.
__global__ __launch_bounds__(256, 2) void down_fused(
    const unsigned short* __restrict__ act_s, const unsigned short* __restrict__ sdown,
    float* __restrict__ out, unsigned short* __restrict__ spart,
    const unsigned short* __restrict__ act_e, const unsigned short* __restrict__ downw,
    unsigned short* __restrict__ eout, const int* __restrict__ ebase,
    const int* __restrict__ cnt) {
  __shared__ __align__(16) char smem[49152];
  int bid = blockIdx.x;
  if (bid < 128) {
    int ks = bid >> 6;
    int rem = bid & 63;  // bx in [0,4), by in [0,16)
    if (ks == 0)
      down_body<0>(smem, rem & 3, rem >> 2, 0, act_s, sdown, out, nullptr,
                   nullptr, nullptr, H_DIM, SI_DIM, 0, 1024, 0);
    else
      down_body<2>(smem, rem & 3, rem >> 2, 0, act_s, sdown, nullptr, spart,
                   nullptr, nullptr, H_DIM, SI_DIM, 1024, 1024, 0);
  } else {
    int b2 = bid - 128;
    int e = b2 >> 6;
    int rem = b2 & 63;  // bx in [0,4), by in [0,16)
    down_body<1>(smem, rem & 3, rem >> 2, e, act_e, downw, nullptr, eout,
                 ebase, cnt, H_DIM, I_DIM, 0, I_DIM, (long)H_DIM * I_DIM);
  }
}

// ---------------------------------------------------------------------------
// Combine: out[t][h] = sg[t]*(p0 + p1) + w0*eout[s0][h] + w1*eout[s1][h].
// p0 = raw fp32 in out, p1 = bf16 in spart. One block per token.
// ---------------------------------------------------------------------------
__global__ __launch_bounds__(256) void combine_kernel(
    float* __restrict__ out, const unsigned short* __restrict__ spart,
    const unsigned short* __restrict__ eout, const float* __restrict__ sg,
    const float2* __restrict__ w01, const int* __restrict__ tok_slot) {
  int t = blockIdx.x;
  int c = threadIdx.x;  // 256 threads x 4 elems = 1024
  float sgr = sg[t];
  float2 wr = w01[t];
  int s0 = tok_slot[2 * t];
  int s1 = tok_slot[2 * t + 1];
  ushort4 p1 = ((const ushort4*)(spart + (long)t * H_DIM))[c];
  ushort4 e0 = ((const ushort4*)(eout + (long)s0 * H_DIM))[c];
  ushort4 e1 = ((const ushort4*)(eout + (long)s1 * H_DIM))[c];
  float4* op = &((float4*)(out + (long)t * H_DIM))[c];
  float4 o = *op;
  o.x = sgr * (o.x + bf2f(p1.x)) + wr.x * bf2f(e0.x) + wr.y * bf2f(e1.x);
  o.y = sgr * (o.y + bf2f(p1.y)) + wr.x * bf2f(e0.y) + wr.y * bf2f(e1.y);
  o.z = sgr * (o.z + bf2f(p1.z)) + wr.x * bf2f(e0.z) + wr.y * bf2f(e1.z);
  o.w = sgr * (o.w + bf2f(p1.w)) + wr.x * bf2f(e0.w) + wr.y * bf2f(e1.w);
  *op = o;
}

// ---------------------------------------------------------------------------
// Workspace map (bytes), total ~63.0 MB (ws proven >= 67.25 MB in round 1):
//   0         xb       bf16[2048][1024]     (reused as spart by down split-K)
//   4194304   gup_b    bf16[8][1024][1024]
//  20971520   down_b   bf16[8][1024][512]
//  29360128   sgate_b  bf16[2048][1024]
//  33554432   sup_b    bf16[2048][1024]
//  37748736   sdown_b  bf16[1024][2048]
//  41943040   act_s    bf16[2048][2048]
//  50331648   act_e    bf16[4096][512]
//  54525952   eout     bf16[4096][1024]
//  62914560   sg / top2 / w01 / cnt / ebase / slot_token / tok_slot
// ---------------------------------------------------------------------------
extern "C" void kernel_launch(void* const* d_in, const int* in_sizes, int n_in,
                              void* d_out, int out_size, void* d_ws, size_t ws_size,
                              hipStream_t stream) {
  const float* x = (const float*)d_in[0];
  const float* rw = (const float*)d_in[1];
  const float* gup = (const float*)d_in[2];
  const float* dwn = (const float*)d_in[3];
  const float* sgw = (const float*)d_in[4];
  const float* suw = (const float*)d_in[5];
  const float* sdw = (const float*)d_in[6];
  const float* segw = (const float*)d_in[7];
  float* out = (float*)d_out;

  char* w = (char*)d_ws;
  unsigned short* xb = (unsigned short*)(w + 0);
  unsigned short* gup_b = (unsigned short*)(w + 4194304L);
  unsigned short* down_b = (unsigned short*)(w + 20971520L);
  unsigned short* sgate_b = (unsigned short*)(w + 29360128L);
  unsigned short* sup_b = (unsigned short*)(w + 33554432L);
  unsigned short* sdown_b = (unsigned short*)(w + 37748736L);
  unsigned short* act_s = (unsigned short*)(w + 41943040L);
  unsigned short* act_e = (unsigned short*)(w + 50331648L);
  unsigned short* eout = (unsigned short*)(w + 54525952L);
  float* sg = (float*)(w + 62914560L);
  int* top2 = (int*)(w + 62922752L);
  float2* w01 = (float2*)(w + 62930944L);
  int* cnt = (int*)(w + 62947328L);
  int* ebase = (int*)(w + 62947584L);
  int* slot_token = (int*)(w + 62947840L);
  int* tok_slot = (int*)(w + 62964224L);
  unsigned short* spart = xb;  // xb dead after swiglu_fused; reuse for split-K partial

  // router (512 blocks, first) + cast of all six tensors (20480 blocks)
  cast_router<<<20992, 256, 0, stream>>>(x, rw, segw, gup, dwn, sgw, suw, sdw,
                                         xb, gup_b, down_b, sgate_b, sup_b,
                                         sdown_b, top2, w01, sg);
  build_lists<<<E_NUM, 256, 0, stream>>>(top2, cnt, ebase, slot_token, tok_slot);
  // fused shared+expert SwiGLU (~384 active = single generation)
  swiglu_fused<<<768, 256, 0, stream>>>(xb, sgate_b, sup_b, act_s, gup_b,
                                        act_e, slot_token, cnt, ebase);
  // fused shared (split-K x2) + expert down-proj, BN=256 (~384 active)
  down_fused<<<640, 256, 0, stream>>>(act_s, sdown_b, out, spart, act_e,
                                      down_b, eout, ebase, cnt);
  // out = sg*(p0+p1) + w0*eout[s0] + w1*eout[s1]
  combine_kernel<<<T_TOK, 256, 0, stream>>>(out, spart, eout, sg, w01, tok_slot);
}